// Round 2
// baseline (1399.506 us; speedup 1.0000x reference)
//
#include <hip/hip_runtime.h>

#define E_      262144
#define NNODES  32768
#define L_      2

typedef __attribute__((ext_vector_type(8))) short  bf16x8;
typedef __attribute__((ext_vector_type(4))) float  f32x4;
typedef __attribute__((ext_vector_type(4))) int    i32x4;

__device__ __forceinline__ float bf2f(unsigned short u) {
    union { unsigned int i; float f; } v; v.i = ((unsigned int)u) << 16; return v.f;
}
__device__ __forceinline__ unsigned short f2bf(float f) {
    union { float f; unsigned int i; } v; v.f = f;
    unsigned int r = v.i + 0x7FFFu + ((v.i >> 16) & 1u);   // round-nearest-even
    return (unsigned short)(r >> 16);
}

// fp32 -> bf16, 4 elems/thread
__global__ __launch_bounds__(256)
void k_cvt(const float* __restrict__ in, unsigned short* __restrict__ out, int n4)
{
    int i = blockIdx.x * 256 + threadIdx.x;
    if (i < n4) {
        float4 v = reinterpret_cast<const float4*>(in)[i];
        ushort4 o;
        o.x = f2bf(v.x); o.y = f2bf(v.y); o.z = f2bf(v.z); o.w = f2bf(v.w);
        reinterpret_cast<ushort4*>(out)[i] = o;
    }
}

// WT[n][k] = bf16(W[k][n])   (W fp32 row-major [K][N])
__global__ __launch_bounds__(256)
void k_transpose(const float* __restrict__ W, unsigned short* __restrict__ WT,
                 int K, int N)
{
    int idx = blockIdx.x * 256 + threadIdx.x;
    if (idx < K * N) {
        int k = idx / N, n = idx % N;
        WT[(size_t)n * K + k] = f2bf(W[idx]);
    }
}

// ---------------------------------------------------------------------------
// C[M][NTOT] = act( A @ W + bias ),  W pre-transposed bf16 WT[NTOT][K].
// GATHER: A row e = concat( nodes[src[e]], edge_attr[e], nodes[dst[e]] ), K=384.
// Tile 64x128, 256 thr (4 waves; wave w owns cols w*32..+31), BK=64,
// LDS XOR-swizzle byte ^= (row&7)<<4 -> ds_read_b128 2-way (free, G4).
// ---------------------------------------------------------------------------
template<int K, int NTOT, bool GATHER, bool RELU>
__global__ __launch_bounds__(256)
void mlp_gemm(const unsigned short* __restrict__ Abase,
              const unsigned short* __restrict__ eattr,
              const int*            __restrict__ ei,      // [2][E]
              const unsigned short* __restrict__ WT,      // [NTOT][K] bf16
              const float*          __restrict__ bias,    // [NTOT] fp32
              unsigned short*       __restrict__ C)       // [M][NTOT] bf16
{
    __shared__ char Alds[64  * 128];
    __shared__ char Blds[128 * 128];

    const int tid  = threadIdx.x;
    const int lane = tid & 63;
    const int w    = tid >> 6;
    const int m0   = blockIdx.x * 64;
    const int n0   = blockIdx.y * 128;

    f32x4 acc[4][2];
#pragma unroll
    for (int m = 0; m < 4; ++m)
#pragma unroll
        for (int n = 0; n < 2; ++n) acc[m][n] = (f32x4){0.f, 0.f, 0.f, 0.f};

    for (int k0 = 0; k0 < K; k0 += 64) {
        // ---- stage A: 64 rows x 8 slots of 16 B ----
#pragma unroll
        for (int it = 0; it < 2; ++it) {
            int c = tid + it * 256;
            int row = c >> 3, slot = c & 7;
            int kk = k0 + slot * 8;
            const unsigned short* p;
            if (GATHER) {
                int e = m0 + row;
                if (kk < 128)        p = Abase + (size_t)ei[e] * 128 + kk;
                else if (kk < 256)   p = eattr + (size_t)e * 128 + (kk - 128);
                else                 p = Abase + (size_t)ei[E_ + e] * 128 + (kk - 256);
            } else {
                p = Abase + (size_t)(m0 + row) * K + kk;
            }
            i32x4 v = *reinterpret_cast<const i32x4*>(p);
            *reinterpret_cast<i32x4*>(Alds + row * 128 + ((slot * 16) ^ ((row & 7) << 4))) = v;
        }
        // ---- stage B: 128 rows x 8 slots ----
#pragma unroll
        for (int it = 0; it < 4; ++it) {
            int c = tid + it * 256;
            int row = c >> 3, slot = c & 7;
            const unsigned short* p = WT + (size_t)(n0 + row) * K + k0 + slot * 8;
            i32x4 v = *reinterpret_cast<const i32x4*>(p);
            *reinterpret_cast<i32x4*>(Blds + row * 128 + ((slot * 16) ^ ((row & 7) << 4))) = v;
        }
        __syncthreads();

#pragma unroll
        for (int ks = 0; ks < 2; ++ks) {
            const int kb = ks * 64 + (lane >> 4) * 16;
            bf16x8 a[4], b[2];
#pragma unroll
            for (int m = 0; m < 4; ++m) {
                int row = m * 16 + (lane & 15);
                a[m] = *reinterpret_cast<const bf16x8*>(Alds + row * 128 + (kb ^ ((row & 7) << 4)));
            }
#pragma unroll
            for (int n = 0; n < 2; ++n) {
                int row = w * 32 + n * 16 + (lane & 15);
                b[n] = *reinterpret_cast<const bf16x8*>(Blds + row * 128 + (kb ^ ((row & 7) << 4)));
            }
#pragma unroll
            for (int m = 0; m < 4; ++m)
#pragma unroll
                for (int n = 0; n < 2; ++n)
                    acc[m][n] = __builtin_amdgcn_mfma_f32_16x16x32_bf16(a[m], b[n], acc[m][n], 0, 0, 0);
        }
        __syncthreads();
    }

    // ---- epilogue: C/D layout col=lane&15, row=(lane>>4)*4+j (m89) ----
#pragma unroll
    for (int n = 0; n < 2; ++n) {
        int colg = n0 + w * 32 + n * 16 + (lane & 15);
        float bi = bias[colg];
#pragma unroll
        for (int m = 0; m < 4; ++m) {
#pragma unroll
            for (int j = 0; j < 4; ++j) {
                int rowg = m0 + m * 16 + (lane >> 4) * 4 + j;
                float r = acc[m][n][j] + bi;
                if (RELU) r = fmaxf(r, 0.f);
                C[(size_t)rowg * NTOT + colg] = f2bf(r);
            }
        }
    }
}

__global__ __launch_bounds__(256)
void k_deg(const int* __restrict__ ei, int* __restrict__ deg)
{
    int e = blockIdx.x * 256 + threadIdx.x;
    atomicAdd(&deg[ei[E_ + e]], 1);
}

__global__ __launch_bounds__(256)
void k_invdeg(const int* __restrict__ deg, float* __restrict__ inv)
{
    int n = blockIdx.x * 256 + threadIdx.x;
    inv[n] = 1.0f / fmaxf((float)deg[n], 1.0f);
}

// agg[dst[e]] += m[e]  (fp32 atomics; 4 cols/thread)
__global__ __launch_bounds__(256)
void k_scatter(const unsigned short* __restrict__ msrc, const int* __restrict__ ei,
               float* __restrict__ agg)
{
    int idx = blockIdx.x * 256 + threadIdx.x;   // E*32 threads
    int e = idx >> 5;
    int c = (idx & 31) * 4;
    int d = ei[E_ + e];
    const uint2 v = *reinterpret_cast<const uint2*>(msrc + (size_t)e * 128 + c);
    float* q = agg + (size_t)d * 128 + c;
    atomicAdd(q + 0, bf2f((unsigned short)(v.x & 0xffffu)));
    atomicAdd(q + 1, bf2f((unsigned short)(v.x >> 16)));
    atomicAdd(q + 2, bf2f((unsigned short)(v.y & 0xffffu)));
    atomicAdd(q + 3, bf2f((unsigned short)(v.y >> 16)));
}

// Fused residual + LayerNorm over rows of 128. Wave/row, 2 cols/lane.
// MODE 0: x = base + res_f32[row]*inv_deg[row];  MODE 1: x = base + res_bf16.
// F32OUT: write fp32 (final output) else bf16.
template<int MODE, bool F32OUT>
__global__ __launch_bounds__(256)
void k_ln(const unsigned short* __restrict__ base,
          const void* __restrict__ res,
          const float* __restrict__ inv_deg,
          const float* __restrict__ g, const float* __restrict__ bb,
          void* __restrict__ outp)
{
    int row  = blockIdx.x * 4 + (threadIdx.x >> 6);
    int lane = threadIdx.x & 63;
    int c    = lane * 2;
    size_t off = (size_t)row * 128 + c;

    float x0 = bf2f(base[off]), x1 = bf2f(base[off + 1]);
    if (MODE == 0) {
        float s = inv_deg[row];
        const float* r = (const float*)res;
        x0 += r[off] * s; x1 += r[off + 1] * s;
    } else {
        const unsigned short* r = (const unsigned short*)res;
        x0 += bf2f(r[off]); x1 += bf2f(r[off + 1]);
    }
    float s = x0 + x1, sq = x0 * x0 + x1 * x1;
#pragma unroll
    for (int m = 1; m < 64; m <<= 1) { s += __shfl_xor(s, m); sq += __shfl_xor(sq, m); }
    float mean = s * (1.f / 128.f);
    float var  = sq * (1.f / 128.f) - mean * mean;
    float rs   = rsqrtf(var + 1e-5f);
    float y0 = (x0 - mean) * rs * g[c]     + bb[c];
    float y1 = (x1 - mean) * rs * g[c + 1] + bb[c + 1];
    if (F32OUT) {
        ((float*)outp)[off]     = y0;
        ((float*)outp)[off + 1] = y1;
    } else {
        ((unsigned short*)outp)[off]     = f2bf(y0);
        ((unsigned short*)outp)[off + 1] = f2bf(y1);
    }
}

// ---------------------------------------------------------------------------
extern "C" void kernel_launch(void* const* d_in, const int* in_sizes, int n_in,
                              void* d_out, int out_size, void* d_ws, size_t ws_size,
                              hipStream_t stream)
{
    const float* x      = (const float*)d_in[0];
    const int*   ei     = (const int*)d_in[1];
    const float* eat0   = (const float*)d_in[2];
    const float* msg_W0 = (const float*)d_in[3];
    const float* msg_b0 = (const float*)d_in[4];
    const float* msg_W1 = (const float*)d_in[5];
    const float* msg_b1 = (const float*)d_in[6];
    const float* msg_W2 = (const float*)d_in[7];
    const float* msg_b2 = (const float*)d_in[8];
    const float* n0g    = (const float*)d_in[9];
    const float* n0b    = (const float*)d_in[10];
    const float* ff_W0  = (const float*)d_in[11];
    const float* ff_b0  = (const float*)d_in[12];
    const float* ff_W1  = (const float*)d_in[13];
    const float* ff_b1  = (const float*)d_in[14];
    const float* n1g    = (const float*)d_in[15];
    const float* n1b    = (const float*)d_in[16];
    const float* e_W0   = (const float*)d_in[17];
    const float* e_b0   = (const float*)d_in[18];
    const float* e_W1   = (const float*)d_in[19];
    const float* e_b1   = (const float*)d_in[20];
    const float* e_W2   = (const float*)d_in[21];
    const float* e_b2   = (const float*)d_in[22];
    const float* eng    = (const float*)d_in[23];
    const float* enb    = (const float*)d_in[24];

    char* ws = (char*)d_ws;
    const size_t MB = (size_t)1 << 20;
    unsigned short* nodes = (unsigned short*)(ws);                 // 8 MB bf16
    unsigned short* edgec = (unsigned short*)(ws + 8 * MB);        // 64 MB bf16
    unsigned short* tmpA  = (unsigned short*)(ws + 72 * MB);       // 64 MB
    unsigned short* tmpB  = (unsigned short*)(ws + 136 * MB);      // 64 MB
    float*          agg   = (float*)(ws + 136 * MB);               // alias tmpB[0:16MB]  (phase-disjoint)
    unsigned short* ffh   = (unsigned short*)(ws + 152 * MB);      // alias tmpB[16:48MB] (phase-disjoint)
    unsigned short* ffo   = tmpA;                                  // alias tmpA (phase-disjoint)
    unsigned short* wt    = (unsigned short*)(ws + 200 * MB);      // ~1 MB bf16
    int*            deg   = (int*)(ws + 201 * MB);                 // 128 KB
    float*          ideg  = (float*)(ws + 201 * MB + 128 * 1024);  // 128 KB

    // weight transposes (fp32 [K][N] -> bf16 [N][K])
    unsigned short* p = wt;
    unsigned short *wt_m0[L_], *wt_m1[L_], *wt_m2[L_], *wt_f0[L_], *wt_f1[L_];
    for (int l = 0; l < L_; ++l) {
        wt_m0[l] = p; p += 384 * 128;
        wt_m1[l] = p; p += 128 * 128;
        wt_m2[l] = p; p += 128 * 128;
        wt_f0[l] = p; p += 128 * 512;
        wt_f1[l] = p; p += 512 * 128;
    }
    unsigned short* wt_e0 = p; p += 384 * 128;
    unsigned short* wt_e1 = p; p += 128 * 128;
    unsigned short* wt_e2 = p; p += 128 * 128;

    auto T = [&](const float* Wp, unsigned short* WTp, int K, int N) {
        k_transpose<<<(K * N + 255) / 256, 256, 0, stream>>>(Wp, WTp, K, N);
    };
    for (int l = 0; l < L_; ++l) {
        T(msg_W0 + l * 384 * 128, wt_m0[l], 384, 128);
        T(msg_W1 + l * 128 * 128, wt_m1[l], 128, 128);
        T(msg_W2 + l * 128 * 128, wt_m2[l], 128, 128);
        T(ff_W0  + l * 128 * 512, wt_f0[l], 128, 512);
        T(ff_W1  + l * 512 * 128, wt_f1[l], 512, 128);
    }
    T(e_W0, wt_e0, 384, 128);   // layer-0 edge update only (layer-1's is dead code)
    T(e_W1, wt_e1, 128, 128);
    T(e_W2, wt_e2, 128, 128);

    // fp32 -> bf16 activations
    k_cvt<<<(NNODES * 128 / 4 + 255) / 256, 256, 0, stream>>>(x,    nodes, NNODES * 128 / 4);
    k_cvt<<<(E_     * 128 / 4 + 255) / 256, 256, 0, stream>>>(eat0, edgec, E_     * 128 / 4);

    hipMemsetAsync(deg, 0, NNODES * sizeof(int), stream);
    k_deg<<<E_ / 256, 256, 0, stream>>>(ei, deg);
    k_invdeg<<<NNODES / 256, 256, 0, stream>>>(deg, ideg);

    const dim3 gE(E_ / 64, 1), gN(NNODES / 64, 1), gF0(NNODES / 64, 4);

    for (int l = 0; l < L_; ++l) {
        // --- message MLP + mean-aggregation + LN ---
        mlp_gemm<384, 128, true,  true ><<<gE, 256, 0, stream>>>(nodes, edgec, ei, wt_m0[l], msg_b0 + l * 128, tmpA);
        mlp_gemm<128, 128, false, true ><<<gE, 256, 0, stream>>>(tmpA, nullptr, nullptr, wt_m1[l], msg_b1 + l * 128, tmpB);
        mlp_gemm<128, 128, false, false><<<gE, 256, 0, stream>>>(tmpB, nullptr, nullptr, wt_m2[l], msg_b2 + l * 128, tmpA);
        hipMemsetAsync(agg, 0, (size_t)NNODES * 128 * sizeof(float), stream);
        k_scatter<<<E_ * 32 / 256, 256, 0, stream>>>(tmpA, ei, agg);
        k_ln<0, false><<<NNODES / 4, 256, 0, stream>>>(nodes, agg, ideg, n0g + l * 128, n0b + l * 128, nodes);
        // --- feedforward + LN ---
        mlp_gemm<128, 512, false, true ><<<gF0, 256, 0, stream>>>(nodes, nullptr, nullptr, wt_f0[l], ff_b0 + l * 512, ffh);
        mlp_gemm<512, 128, false, false><<<gN, 256, 0, stream>>>(ffh, nullptr, nullptr, wt_f1[l], ff_b1 + l * 128, ffo);
        if (l == L_ - 1) {
            // final live op: write fp32 straight to d_out
            k_ln<1, true><<<NNODES / 4, 256, 0, stream>>>(nodes, ffo, nullptr, n1g + l * 128, n1b + l * 128, d_out);
        } else {
            k_ln<1, false><<<NNODES / 4, 256, 0, stream>>>(nodes, ffo, nullptr, n1g + l * 128, n1b + l * 128, nodes);
        }
        // --- edge update (only layer 0: the last layer's edge MLP never reaches the output) ---
        if (l == 0) {
            mlp_gemm<384, 128, true,  true ><<<gE, 256, 0, stream>>>(nodes, edgec, ei, wt_e0, e_b0, tmpA);
            mlp_gemm<128, 128, false, true ><<<gE, 256, 0, stream>>>(tmpA, nullptr, nullptr, wt_e1, e_b1, tmpB);
            mlp_gemm<128, 128, false, false><<<gE, 256, 0, stream>>>(tmpB, nullptr, nullptr, wt_e2, e_b2, tmpA);
            k_ln<1, false><<<E_ / 4, 256, 0, stream>>>(edgec, tmpA, nullptr, eng, enb, edgec);
        }
    }
}

// Round 3
// 597.407 us; speedup vs baseline: 2.3426x; 2.3426x over previous
//
#include <hip/hip_runtime.h>

#define E_      262144
#define NNODES  32768
#define L_      2

typedef __attribute__((ext_vector_type(8))) short  bf16x8;
typedef __attribute__((ext_vector_type(4))) float  f32x4;
typedef __attribute__((ext_vector_type(4))) int    i32x4;

__device__ __forceinline__ float bf2f(unsigned short u) {
    union { unsigned int i; float f; } v; v.i = ((unsigned int)u) << 16; return v.f;
}
__device__ __forceinline__ unsigned short f2bf(float f) {
    union { float f; unsigned int i; } v; v.f = f;
    unsigned int r = v.i + 0x7FFFu + ((v.i >> 16) & 1u);   // round-nearest-even
    return (unsigned short)(r >> 16);
}

// fp32 -> bf16, 4 elems/thread
__global__ __launch_bounds__(256)
void k_cvt(const float* __restrict__ in, unsigned short* __restrict__ out, int n4)
{
    int i = blockIdx.x * 256 + threadIdx.x;
    if (i < n4) {
        float4 v = reinterpret_cast<const float4*>(in)[i];
        ushort4 o;
        o.x = f2bf(v.x); o.y = f2bf(v.y); o.z = f2bf(v.z); o.w = f2bf(v.w);
        reinterpret_cast<ushort4*>(out)[i] = o;
    }
}

// WT[n][k] = bf16(W[k][n])   (W fp32 row-major [K][N])
__global__ __launch_bounds__(256)
void k_transpose(const float* __restrict__ W, unsigned short* __restrict__ WT,
                 int K, int N)
{
    int idx = blockIdx.x * 256 + threadIdx.x;
    if (idx < K * N) {
        int k = idx / N, n = idx % N;
        WT[(size_t)n * K + k] = f2bf(W[idx]);
    }
}

// ---------------------------------------------------------------------------
// GEMM: C[M][NTOT] = act( A @ W + bias ), W pre-transposed bf16 WT[NTOT][K].
// GATHER: A row e = concat( nodes[src[e]], edge_attr[e], nodes[dst[e]] ), K=384.
// Tile 64x128, 4 waves, BK=64, XOR-swizzled LDS (G4).
// ---------------------------------------------------------------------------
template<int K, int NTOT, bool GATHER, bool RELU>
__global__ __launch_bounds__(256)
void mlp_gemm(const unsigned short* __restrict__ Abase,
              const unsigned short* __restrict__ eattr,
              const int*            __restrict__ ei,      // [2][E]
              const unsigned short* __restrict__ WT,      // [NTOT][K] bf16
              const float*          __restrict__ bias,    // [NTOT] fp32
              unsigned short*       __restrict__ C)       // [M][NTOT] bf16
{
    __shared__ char Alds[64  * 128];
    __shared__ char Blds[128 * 128];

    const int tid  = threadIdx.x;
    const int lane = tid & 63;
    const int w    = tid >> 6;
    const int m0   = blockIdx.x * 64;
    const int n0   = blockIdx.y * 128;

    f32x4 acc[4][2];
#pragma unroll
    for (int m = 0; m < 4; ++m)
#pragma unroll
        for (int n = 0; n < 2; ++n) acc[m][n] = (f32x4){0.f, 0.f, 0.f, 0.f};

    for (int k0 = 0; k0 < K; k0 += 64) {
#pragma unroll
        for (int it = 0; it < 2; ++it) {
            int c = tid + it * 256;
            int row = c >> 3, slot = c & 7;
            int kk = k0 + slot * 8;
            const unsigned short* p;
            if (GATHER) {
                int e = m0 + row;
                if (kk < 128)        p = Abase + (size_t)ei[e] * 128 + kk;
                else if (kk < 256)   p = eattr + (size_t)e * 128 + (kk - 128);
                else                 p = Abase + (size_t)ei[E_ + e] * 128 + (kk - 256);
            } else {
                p = Abase + (size_t)(m0 + row) * K + kk;
            }
            i32x4 v = *reinterpret_cast<const i32x4*>(p);
            *reinterpret_cast<i32x4*>(Alds + row * 128 + ((slot * 16) ^ ((row & 7) << 4))) = v;
        }
#pragma unroll
        for (int it = 0; it < 4; ++it) {
            int c = tid + it * 256;
            int row = c >> 3, slot = c & 7;
            const unsigned short* p = WT + (size_t)(n0 + row) * K + k0 + slot * 8;
            i32x4 v = *reinterpret_cast<const i32x4*>(p);
            *reinterpret_cast<i32x4*>(Blds + row * 128 + ((slot * 16) ^ ((row & 7) << 4))) = v;
        }
        __syncthreads();

#pragma unroll
        for (int ks = 0; ks < 2; ++ks) {
            const int kb = ks * 64 + (lane >> 4) * 16;
            bf16x8 a[4], b[2];
#pragma unroll
            for (int m = 0; m < 4; ++m) {
                int row = m * 16 + (lane & 15);
                a[m] = *reinterpret_cast<const bf16x8*>(Alds + row * 128 + (kb ^ ((row & 7) << 4)));
            }
#pragma unroll
            for (int n = 0; n < 2; ++n) {
                int row = w * 32 + n * 16 + (lane & 15);
                b[n] = *reinterpret_cast<const bf16x8*>(Blds + row * 128 + (kb ^ ((row & 7) << 4)));
            }
#pragma unroll
            for (int m = 0; m < 4; ++m)
#pragma unroll
                for (int n = 0; n < 2; ++n)
                    acc[m][n] = __builtin_amdgcn_mfma_f32_16x16x32_bf16(a[m], b[n], acc[m][n], 0, 0, 0);
        }
        __syncthreads();
    }

    // epilogue: C/D layout col=lane&15, row=(lane>>4)*4+j (m89)
#pragma unroll
    for (int n = 0; n < 2; ++n) {
        int colg = n0 + w * 32 + n * 16 + (lane & 15);
        float bi = bias[colg];
#pragma unroll
        for (int m = 0; m < 4; ++m) {
#pragma unroll
            for (int j = 0; j < 4; ++j) {
                int rowg = m0 + m * 16 + (lane >> 4) * 4 + j;
                float r = acc[m][n][j] + bi;
                if (RELU) r = fmaxf(r, 0.f);
                C[(size_t)rowg * NTOT + colg] = f2bf(r);
            }
        }
    }
}

__global__ __launch_bounds__(256)
void k_deg(const int* __restrict__ ei, int* __restrict__ deg)
{
    int e = blockIdx.x * 256 + threadIdx.x;
    atomicAdd(&deg[ei[E_ + e]], 1);
}

// exclusive scan of deg[32768] -> off[32769], one block of 1024 threads
__global__ __launch_bounds__(1024)
void k_scan(const int* __restrict__ deg, int* __restrict__ off)
{
    __shared__ int part[1024];
    const int t = threadIdx.x;
    const int base = t * 32;
    int loc[32];
    int s = 0;
#pragma unroll
    for (int i = 0; i < 32; ++i) { loc[i] = s; s += deg[base + i]; }
    part[t] = s;
    __syncthreads();
    for (int d = 1; d < 1024; d <<= 1) {
        int v = (t >= d) ? part[t - d] : 0;
        __syncthreads();
        part[t] += v;
        __syncthreads();
    }
    const int pre = (t == 0) ? 0 : part[t - 1];
#pragma unroll
    for (int i = 0; i < 32; ++i) off[base + i] = pre + loc[i];
    if (t == 1023) off[NNODES] = pre + s;   // = E
}

// elist bucket fill: cursor starts as a copy of off
__global__ __launch_bounds__(256)
void k_bucket(const int* __restrict__ ei, int* __restrict__ cursor, int* __restrict__ elist)
{
    int e = blockIdx.x * 256 + threadIdx.x;
    int d = ei[E_ + e];
    int pos = atomicAdd(&cursor[d], 1);
    elist[pos] = e;
}

// Fused: agg = mean_{e in CSR[v]} m[e];  out = LN(nodes_in[v] + agg).
// One wave per node; 2 cols/lane; each edge iteration = one coalesced 256B row read.
__global__ __launch_bounds__(256)
void k_aggln(const unsigned short* __restrict__ m,      // [E][128] bf16
             const int* __restrict__ off, const int* __restrict__ elist,
             const unsigned short* __restrict__ nodes_in,
             const float* __restrict__ g, const float* __restrict__ bb,
             unsigned short* __restrict__ nodes_out)
{
    const int v    = blockIdx.x * 4 + (threadIdx.x >> 6);
    const int lane = threadIdx.x & 63;
    const int c    = lane * 2;
    const int beg  = off[v], end = off[v + 1];

    float a0 = 0.f, a1 = 0.f;
    for (int i = beg; i < end; ++i) {
        int e = elist[i];
        unsigned int u = *reinterpret_cast<const unsigned int*>(m + (size_t)e * 128 + c);
        a0 += bf2f((unsigned short)(u & 0xffffu));
        a1 += bf2f((unsigned short)(u >> 16));
    }
    const float inv = 1.f / fmaxf((float)(end - beg), 1.f);
    const size_t o = (size_t)v * 128 + c;
    float x0 = bf2f(nodes_in[o])     + a0 * inv;
    float x1 = bf2f(nodes_in[o + 1]) + a1 * inv;

    float s = x0 + x1, sq = x0 * x0 + x1 * x1;
#pragma unroll
    for (int mm = 1; mm < 64; mm <<= 1) { s += __shfl_xor(s, mm); sq += __shfl_xor(sq, mm); }
    float mean = s * (1.f / 128.f);
    float var  = sq * (1.f / 128.f) - mean * mean;
    float rs   = rsqrtf(var + 1e-5f);
    nodes_out[o]     = f2bf((x0 - mean) * rs * g[c]     + bb[c]);
    nodes_out[o + 1] = f2bf((x1 - mean) * rs * g[c + 1] + bb[c + 1]);
}

// Fused residual + LayerNorm (bf16 residual). F32OUT: write fp32 (final output).
template<bool F32OUT>
__global__ __launch_bounds__(256)
void k_ln(const unsigned short* __restrict__ base,
          const unsigned short* __restrict__ res,
          const float* __restrict__ g, const float* __restrict__ bb,
          void* __restrict__ outp)
{
    int row  = blockIdx.x * 4 + (threadIdx.x >> 6);
    int lane = threadIdx.x & 63;
    int c    = lane * 2;
    size_t off = (size_t)row * 128 + c;

    float x0 = bf2f(base[off])     + bf2f(res[off]);
    float x1 = bf2f(base[off + 1]) + bf2f(res[off + 1]);
    float s = x0 + x1, sq = x0 * x0 + x1 * x1;
#pragma unroll
    for (int m = 1; m < 64; m <<= 1) { s += __shfl_xor(s, m); sq += __shfl_xor(sq, m); }
    float mean = s * (1.f / 128.f);
    float var  = sq * (1.f / 128.f) - mean * mean;
    float rs   = rsqrtf(var + 1e-5f);
    float y0 = (x0 - mean) * rs * g[c]     + bb[c];
    float y1 = (x1 - mean) * rs * g[c + 1] + bb[c + 1];
    if (F32OUT) {
        ((float*)outp)[off]     = y0;
        ((float*)outp)[off + 1] = y1;
    } else {
        ((unsigned short*)outp)[off]     = f2bf(y0);
        ((unsigned short*)outp)[off + 1] = f2bf(y1);
    }
}

// ---------------------------------------------------------------------------
extern "C" void kernel_launch(void* const* d_in, const int* in_sizes, int n_in,
                              void* d_out, int out_size, void* d_ws, size_t ws_size,
                              hipStream_t stream)
{
    const float* x      = (const float*)d_in[0];
    const int*   ei     = (const int*)d_in[1];
    const float* eat0   = (const float*)d_in[2];
    const float* msg_W0 = (const float*)d_in[3];
    const float* msg_b0 = (const float*)d_in[4];
    const float* msg_W1 = (const float*)d_in[5];
    const float* msg_b1 = (const float*)d_in[6];
    const float* msg_W2 = (const float*)d_in[7];
    const float* msg_b2 = (const float*)d_in[8];
    const float* n0g    = (const float*)d_in[9];
    const float* n0b    = (const float*)d_in[10];
    const float* ff_W0  = (const float*)d_in[11];
    const float* ff_b0  = (const float*)d_in[12];
    const float* ff_W1  = (const float*)d_in[13];
    const float* ff_b1  = (const float*)d_in[14];
    const float* n1g    = (const float*)d_in[15];
    const float* n1b    = (const float*)d_in[16];
    const float* e_W0   = (const float*)d_in[17];
    const float* e_b0   = (const float*)d_in[18];
    const float* e_W1   = (const float*)d_in[19];
    const float* e_b1   = (const float*)d_in[20];
    const float* e_W2   = (const float*)d_in[21];
    const float* e_b2   = (const float*)d_in[22];
    const float* eng    = (const float*)d_in[23];
    const float* enb    = (const float*)d_in[24];

    char* ws = (char*)d_ws;
    const size_t MB = (size_t)1 << 20;
    unsigned short* nodes = (unsigned short*)(ws);                 // 8 MB bf16
    unsigned short* edgec = (unsigned short*)(ws + 8 * MB);        // 64 MB bf16
    unsigned short* tmpA  = (unsigned short*)(ws + 72 * MB);       // 64 MB
    unsigned short* tmpB  = (unsigned short*)(ws + 136 * MB);      // 64 MB
    unsigned short* ffh   = (unsigned short*)(ws + 136 * MB);      // alias tmpB (phase-disjoint)
    unsigned short* ffo   = tmpA;                                  // alias tmpA (phase-disjoint)
    unsigned short* wt    = (unsigned short*)(ws + 200 * MB);      // ~1 MB bf16
    int*            deg   = (int*)(ws + 202 * MB);                 // 128 KB
    int*            off   = (int*)(ws + 202 * MB + 256 * 1024);    // 128 KB + 4
    int*            cur   = (int*)(ws + 202 * MB + 512 * 1024);    // 128 KB
    int*            elist = (int*)(ws + 202 * MB + 768 * 1024);    // 1 MB

    // weight transposes (fp32 [K][N] -> bf16 [N][K])
    unsigned short* p = wt;
    unsigned short *wt_m0[L_], *wt_m1[L_], *wt_m2[L_], *wt_f0[L_], *wt_f1[L_];
    for (int l = 0; l < L_; ++l) {
        wt_m0[l] = p; p += 384 * 128;
        wt_m1[l] = p; p += 128 * 128;
        wt_m2[l] = p; p += 128 * 128;
        wt_f0[l] = p; p += 128 * 512;
        wt_f1[l] = p; p += 512 * 128;
    }
    unsigned short* wt_e0 = p; p += 384 * 128;
    unsigned short* wt_e1 = p; p += 128 * 128;
    unsigned short* wt_e2 = p; p += 128 * 128;

    auto T = [&](const float* Wp, unsigned short* WTp, int K, int N) {
        k_transpose<<<(K * N + 255) / 256, 256, 0, stream>>>(Wp, WTp, K, N);
    };
    for (int l = 0; l < L_; ++l) {
        T(msg_W0 + l * 384 * 128, wt_m0[l], 384, 128);
        T(msg_W1 + l * 128 * 128, wt_m1[l], 128, 128);
        T(msg_W2 + l * 128 * 128, wt_m2[l], 128, 128);
        T(ff_W0  + l * 128 * 512, wt_f0[l], 128, 512);
        T(ff_W1  + l * 512 * 128, wt_f1[l], 512, 128);
    }
    T(e_W0, wt_e0, 384, 128);   // layer-0 edge update only (layer-1's is dead code)
    T(e_W1, wt_e1, 128, 128);
    T(e_W2, wt_e2, 128, 128);

    // fp32 -> bf16 activations
    k_cvt<<<(NNODES * 128 / 4 + 255) / 256, 256, 0, stream>>>(x,    nodes, NNODES * 128 / 4);
    k_cvt<<<(E_     * 128 / 4 + 255) / 256, 256, 0, stream>>>(eat0, edgec, E_     * 128 / 4);

    // CSR build (once — edge_index constant across layers)
    hipMemsetAsync(deg, 0, NNODES * sizeof(int), stream);
    k_deg<<<E_ / 256, 256, 0, stream>>>(ei, deg);
    k_scan<<<1, 1024, 0, stream>>>(deg, off);
    hipMemcpyAsync(cur, off, NNODES * sizeof(int), hipMemcpyDeviceToDevice, stream);
    k_bucket<<<E_ / 256, 256, 0, stream>>>(ei, cur, elist);

    const dim3 gE(E_ / 64, 1), gN(NNODES / 64, 1), gF0(NNODES / 64, 4);

    for (int l = 0; l < L_; ++l) {
        // --- message MLP + mean-aggregation + LN (CSR gather, no atomics) ---
        mlp_gemm<384, 128, true,  true ><<<gE, 256, 0, stream>>>(nodes, edgec, ei, wt_m0[l], msg_b0 + l * 128, tmpA);
        mlp_gemm<128, 128, false, true ><<<gE, 256, 0, stream>>>(tmpA, nullptr, nullptr, wt_m1[l], msg_b1 + l * 128, tmpB);
        mlp_gemm<128, 128, false, false><<<gE, 256, 0, stream>>>(tmpB, nullptr, nullptr, wt_m2[l], msg_b2 + l * 128, tmpA);
        k_aggln<<<NNODES / 4, 256, 0, stream>>>(tmpA, off, elist, nodes, n0g + l * 128, n0b + l * 128, nodes);
        // --- feedforward + LN ---
        mlp_gemm<128, 512, false, true ><<<gF0, 256, 0, stream>>>(nodes, nullptr, nullptr, wt_f0[l], ff_b0 + l * 512, ffh);
        mlp_gemm<512, 128, false, false><<<gN, 256, 0, stream>>>(ffh, nullptr, nullptr, wt_f1[l], ff_b1 + l * 128, ffo);
        if (l == L_ - 1) {
            k_ln<true ><<<NNODES / 4, 256, 0, stream>>>(nodes, ffo, n1g + l * 128, n1b + l * 128, d_out);
        } else {
            k_ln<false><<<NNODES / 4, 256, 0, stream>>>(nodes, ffo, n1g + l * 128, n1b + l * 128, nodes);
        }
        // --- edge update (only layer 0: the last layer's edge MLP never reaches the output) ---
        if (l == 0) {
            mlp_gemm<384, 128, true,  true ><<<gE, 256, 0, stream>>>(nodes, edgec, ei, wt_e0, e_b0, tmpA);
            mlp_gemm<128, 128, false, true ><<<gE, 256, 0, stream>>>(tmpA, nullptr, nullptr, wt_e1, e_b1, tmpB);
            mlp_gemm<128, 128, false, false><<<gE, 256, 0, stream>>>(tmpB, nullptr, nullptr, wt_e2, e_b2, tmpA);
            k_ln<false><<<E_ / 4, 256, 0, stream>>>(edgec, tmpA, eng, enb, edgec);
        }
    }
}

// Round 4
// 578.904 us; speedup vs baseline: 2.4175x; 1.0320x over previous
//
#include <hip/hip_runtime.h>

#define E_      262144
#define NNODES  32768
#define L_      2

typedef __attribute__((ext_vector_type(8))) short  bf16x8;
typedef __attribute__((ext_vector_type(4))) float  f32x4;

typedef __attribute__((address_space(1))) const unsigned int gu32;
typedef __attribute__((address_space(3))) unsigned int       lu32;

__device__ __forceinline__ void gl16(const void* g, void* l) {
    // async global->LDS, 16B per lane; LDS dest = wave-uniform base + lane*16
    __builtin_amdgcn_global_load_lds((gu32*)g, (lu32*)l, 16, 0, 0);
}

__device__ __forceinline__ float bf2f(unsigned short u) {
    union { unsigned int i; float f; } v; v.i = ((unsigned int)u) << 16; return v.f;
}
__device__ __forceinline__ unsigned short f2bf(float f) {
    union { float f; unsigned int i; } v; v.f = f;
    unsigned int r = v.i + 0x7FFFu + ((v.i >> 16) & 1u);   // round-nearest-even
    return (unsigned short)(r >> 16);
}

// combined fp32->bf16 for nodes + edge_attr
__global__ __launch_bounds__(256)
void k_cvt2(const float* __restrict__ a, unsigned short* __restrict__ oa, int n4a,
            const float* __restrict__ b, unsigned short* __restrict__ ob, int n4b)
{
    int i = blockIdx.x * 256 + threadIdx.x;
    if (i < n4a) {
        float4 v = reinterpret_cast<const float4*>(a)[i];
        ushort4 o; o.x = f2bf(v.x); o.y = f2bf(v.y); o.z = f2bf(v.z); o.w = f2bf(v.w);
        reinterpret_cast<ushort4*>(oa)[i] = o;
    } else if (i < n4a + n4b) {
        int j = i - n4a;
        float4 v = reinterpret_cast<const float4*>(b)[j];
        ushort4 o; o.x = f2bf(v.x); o.y = f2bf(v.y); o.z = f2bf(v.z); o.w = f2bf(v.w);
        reinterpret_cast<ushort4*>(ob)[j] = o;
    }
}

// batched weight transpose: 13 matrices in one dispatch. [K][N] fp32 -> [N][K] bf16
struct TD  { const float* s; unsigned short* d; int off; int K; int nsh; };
struct TDA { TD v[13]; int total; };

__global__ __launch_bounds__(256)
void k_transpose_all(TDA t)
{
    int idx = blockIdx.x * 256 + threadIdx.x;
    if (idx >= t.total) return;
    int j = 0;
#pragma unroll
    for (int m = 1; m < 13; ++m) if (idx >= t.v[m].off) j = m;
    const TD& td = t.v[j];
    int local = idx - td.off;
    int k = local >> td.nsh;
    int n = local & ((1 << td.nsh) - 1);
    td.d[(size_t)n * td.K + k] = f2bf(td.s[local]);
}

// ---------------------------------------------------------------------------
// GEMM: C[M][NTOT] = act( A @ W + bias ), W pre-transposed bf16 WT[NTOT][K].
// GATHER: A row e = concat( nodes[src[e]], edge_attr[e], nodes[dst[e]] ), K=384.
// Tile BM x 128, 256 thr (2x2 wave grid, per-wave MI x 4 frags of 16x16), BK=64.
// Staging via global_load_lds width=16; XOR-swizzle (byte ^= (row&7)<<4) applied
// by pre-permuting the per-lane GLOBAL source slot (rule 21: linear LDS dest,
// inverse-swizzled source, swizzled read).
// ---------------------------------------------------------------------------
template<int BM, int K, int NTOT, bool GATHER, bool RELU>
__global__ __launch_bounds__(256)
void mlp_gemm(const unsigned short* __restrict__ Abase,
              const unsigned short* __restrict__ eattr,
              const int*            __restrict__ ei,      // [2][E]
              const unsigned short* __restrict__ WT,      // [NTOT][K] bf16
              const float*          __restrict__ bias,    // [NTOT] fp32
              unsigned short*       __restrict__ C)       // [M][NTOT] bf16
{
    constexpr int MI = BM / 32;          // A-frags per wave (m dim): 2 or 4
    __shared__ unsigned short Alds[BM * 64];    // BM rows x 64 bf16 (128B/row)
    __shared__ unsigned short Blds[128 * 64];

    const int tid  = threadIdx.x;
    const int lane = tid & 63;
    const int w    = tid >> 6;
    const int wr   = w >> 1, wc = w & 1;        // 2x2 wave grid
    const int m0   = blockIdx.x * BM;
    const int n0   = blockIdx.y * 128;

    const int lrow = lane >> 3;                       // row within an 8-row issue
    const int soff = ((lane & 7) ^ lrow) * 8;         // inverse-swizzled slot (elems)

    // per-issue global row pointers (include lane slot offset)
    const unsigned short *pS[MI], *pD[MI], *pE[MI], *pB[4];
#pragma unroll
    for (int i = 0; i < MI; ++i) {
        int r = w * (BM / 4) + i * 8 + lrow;
        if (GATHER) {
            int e = m0 + r;
            pS[i] = Abase + (size_t)ei[e]      * 128 + soff;
            pD[i] = Abase + (size_t)ei[E_ + e] * 128 + soff;
            pE[i] = eattr + (size_t)e          * 128 + soff;
        } else {
            pS[i] = Abase + (size_t)(m0 + r) * K + soff;
        }
    }
#pragma unroll
    for (int i = 0; i < 4; ++i)
        pB[i] = WT + (size_t)(n0 + w * 32 + i * 8 + lrow) * K + soff;

    f32x4 acc[MI][4];
#pragma unroll
    for (int m = 0; m < MI; ++m)
#pragma unroll
        for (int n = 0; n < 4; ++n) acc[m][n] = (f32x4){0.f, 0.f, 0.f, 0.f};

#pragma unroll
    for (int k0 = 0; k0 < K; k0 += 64) {
        // ---- stage A (BM/32 issues/wave) + B (4 issues/wave) via DMA ----
#pragma unroll
        for (int i = 0; i < MI; ++i) {
            const unsigned short* pa;
            if (GATHER) {
                int off = k0 & 64;
                pa = (k0 < 128 ? pS[i] : (k0 < 256 ? pE[i] : pD[i])) + off;
            } else {
                pa = pS[i] + k0;
            }
            gl16(pa, Alds + (w * (BM / 4) + i * 8) * 64);
        }
#pragma unroll
        for (int i = 0; i < 4; ++i)
            gl16(pB[i] + k0, Blds + (w * 32 + i * 8) * 64);
        __syncthreads();   // drains vmcnt before barrier (m97 structure)

#pragma unroll
        for (int ks = 0; ks < 2; ++ks) {
            const int kb = ks * 64 + (lane >> 4) * 16;   // byte offset within row
            bf16x8 a[MI], b[4];
#pragma unroll
            for (int m = 0; m < MI; ++m) {
                int row = wr * (BM / 2) + m * 16 + (lane & 15);
                a[m] = *reinterpret_cast<const bf16x8*>(
                    (const char*)Alds + row * 128 + (kb ^ ((row & 7) << 4)));
            }
#pragma unroll
            for (int n = 0; n < 4; ++n) {
                int row = wc * 64 + n * 16 + (lane & 15);
                b[n] = *reinterpret_cast<const bf16x8*>(
                    (const char*)Blds + row * 128 + (kb ^ ((row & 7) << 4)));
            }
#pragma unroll
            for (int m = 0; m < MI; ++m)
#pragma unroll
                for (int n = 0; n < 4; ++n)
                    acc[m][n] = __builtin_amdgcn_mfma_f32_16x16x32_bf16(a[m], b[n], acc[m][n], 0, 0, 0);
        }
        __syncthreads();
    }

    // epilogue: C/D layout col=lane&15, row=(lane>>4)*4+j (m89)
#pragma unroll
    for (int n = 0; n < 4; ++n) {
        int colg = n0 + wc * 64 + n * 16 + (lane & 15);
        float bi = bias[colg];
#pragma unroll
        for (int m = 0; m < MI; ++m) {
            int rowg = m0 + wr * (BM / 2) + m * 16 + (lane >> 4) * 4;
            unsigned short* cp = C + (size_t)rowg * NTOT + colg;
#pragma unroll
            for (int j = 0; j < 4; ++j) {
                float r = acc[m][n][j] + bi;
                if (RELU) r = fmaxf(r, 0.f);
                cp[(size_t)j * NTOT] = f2bf(r);
            }
        }
    }
}

__global__ __launch_bounds__(256)
void k_deg(const int* __restrict__ ei, int* __restrict__ deg)
{
    int e = blockIdx.x * 256 + threadIdx.x;
    atomicAdd(&deg[ei[E_ + e]], 1);
}

// exclusive scan of deg[32768] -> off[32769], one block of 1024 threads
__global__ __launch_bounds__(1024)
void k_scan(const int* __restrict__ deg, int* __restrict__ off)
{
    __shared__ int part[1024];
    const int t = threadIdx.x;
    const int base = t * 32;
    int loc[32];
    int s = 0;
#pragma unroll
    for (int i = 0; i < 32; ++i) { loc[i] = s; s += deg[base + i]; }
    part[t] = s;
    __syncthreads();
    for (int d = 1; d < 1024; d <<= 1) {
        int v = (t >= d) ? part[t - d] : 0;
        __syncthreads();
        part[t] += v;
        __syncthreads();
    }
    const int pre = (t == 0) ? 0 : part[t - 1];
#pragma unroll
    for (int i = 0; i < 32; ++i) off[base + i] = pre + loc[i];
    if (t == 1023) off[NNODES] = pre + s;   // = E
}

// elist bucket fill: cursor starts as a copy of off
__global__ __launch_bounds__(256)
void k_bucket(const int* __restrict__ ei, int* __restrict__ cursor, int* __restrict__ elist)
{
    int e = blockIdx.x * 256 + threadIdx.x;
    int d = ei[E_ + e];
    int pos = atomicAdd(&cursor[d], 1);
    elist[pos] = e;
}

// Fused: agg = mean_{e in CSR[v]} m[e];  out = LN(nodes_in[v] + agg).
__global__ __launch_bounds__(256)
void k_aggln(const unsigned short* __restrict__ m,      // [E][128] bf16
             const int* __restrict__ off, const int* __restrict__ elist,
             const unsigned short* __restrict__ nodes_in,
             const float* __restrict__ g, const float* __restrict__ bb,
             unsigned short* __restrict__ nodes_out)
{
    const int v    = blockIdx.x * 4 + (threadIdx.x >> 6);
    const int lane = threadIdx.x & 63;
    const int c    = lane * 2;
    const int beg  = off[v], end = off[v + 1];

    float a0 = 0.f, a1 = 0.f;
    for (int i = beg; i < end; ++i) {
        int e = elist[i];
        unsigned int u = *reinterpret_cast<const unsigned int*>(m + (size_t)e * 128 + c);
        a0 += bf2f((unsigned short)(u & 0xffffu));
        a1 += bf2f((unsigned short)(u >> 16));
    }
    const float inv = 1.f / fmaxf((float)(end - beg), 1.f);
    const size_t o = (size_t)v * 128 + c;
    float x0 = bf2f(nodes_in[o])     + a0 * inv;
    float x1 = bf2f(nodes_in[o + 1]) + a1 * inv;

    float s = x0 + x1, sq = x0 * x0 + x1 * x1;
#pragma unroll
    for (int mm = 1; mm < 64; mm <<= 1) { s += __shfl_xor(s, mm); sq += __shfl_xor(sq, mm); }
    float mean = s * (1.f / 128.f);
    float var  = sq * (1.f / 128.f) - mean * mean;
    float rs   = rsqrtf(var + 1e-5f);
    nodes_out[o]     = f2bf((x0 - mean) * rs * g[c]     + bb[c]);
    nodes_out[o + 1] = f2bf((x1 - mean) * rs * g[c + 1] + bb[c + 1]);
}

// Fused residual + LayerNorm (bf16 residual). F32OUT: write fp32 (final output).
template<bool F32OUT>
__global__ __launch_bounds__(256)
void k_ln(const unsigned short* __restrict__ base,
          const unsigned short* __restrict__ res,
          const float* __restrict__ g, const float* __restrict__ bb,
          void* __restrict__ outp)
{
    int row  = blockIdx.x * 4 + (threadIdx.x >> 6);
    int lane = threadIdx.x & 63;
    int c    = lane * 2;
    size_t off = (size_t)row * 128 + c;

    float x0 = bf2f(base[off])     + bf2f(res[off]);
    float x1 = bf2f(base[off + 1]) + bf2f(res[off + 1]);
    float s = x0 + x1, sq = x0 * x0 + x1 * x1;
#pragma unroll
    for (int m = 1; m < 64; m <<= 1) { s += __shfl_xor(s, m); sq += __shfl_xor(sq, m); }
    float mean = s * (1.f / 128.f);
    float var  = sq * (1.f / 128.f) - mean * mean;
    float rs   = rsqrtf(var + 1e-5f);
    float y0 = (x0 - mean) * rs * g[c]     + bb[c];
    float y1 = (x1 - mean) * rs * g[c + 1] + bb[c + 1];
    if (F32OUT) {
        ((float*)outp)[off]     = y0;
        ((float*)outp)[off + 1] = y1;
    } else {
        ((unsigned short*)outp)[off]     = f2bf(y0);
        ((unsigned short*)outp)[off + 1] = f2bf(y1);
    }
}

// ---------------------------------------------------------------------------
extern "C" void kernel_launch(void* const* d_in, const int* in_sizes, int n_in,
                              void* d_out, int out_size, void* d_ws, size_t ws_size,
                              hipStream_t stream)
{
    const float* x      = (const float*)d_in[0];
    const int*   ei     = (const int*)d_in[1];
    const float* eat0   = (const float*)d_in[2];
    const float* msg_W0 = (const float*)d_in[3];
    const float* msg_b0 = (const float*)d_in[4];
    const float* msg_W1 = (const float*)d_in[5];
    const float* msg_b1 = (const float*)d_in[6];
    const float* msg_W2 = (const float*)d_in[7];
    const float* msg_b2 = (const float*)d_in[8];
    const float* n0g    = (const float*)d_in[9];
    const float* n0b    = (const float*)d_in[10];
    const float* ff_W0  = (const float*)d_in[11];
    const float* ff_b0  = (const float*)d_in[12];
    const float* ff_W1  = (const float*)d_in[13];
    const float* ff_b1  = (const float*)d_in[14];
    const float* n1g    = (const float*)d_in[15];
    const float* n1b    = (const float*)d_in[16];
    const float* e_W0   = (const float*)d_in[17];
    const float* e_b0   = (const float*)d_in[18];
    const float* e_W1   = (const float*)d_in[19];
    const float* e_b1   = (const float*)d_in[20];
    const float* e_W2   = (const float*)d_in[21];
    const float* e_b2   = (const float*)d_in[22];
    const float* eng    = (const float*)d_in[23];
    const float* enb    = (const float*)d_in[24];

    char* ws = (char*)d_ws;
    const size_t MB = (size_t)1 << 20;
    unsigned short* nodes = (unsigned short*)(ws);                 // 8 MB bf16
    unsigned short* edgec = (unsigned short*)(ws + 8 * MB);        // 64 MB bf16
    unsigned short* tmpA  = (unsigned short*)(ws + 72 * MB);       // 64 MB
    unsigned short* tmpB  = (unsigned short*)(ws + 136 * MB);      // 64 MB
    unsigned short* ffh   = (unsigned short*)(ws + 136 * MB);      // alias tmpB (phase-disjoint)
    unsigned short* ffo   = tmpA;                                  // alias tmpA (phase-disjoint)
    unsigned short* wt    = (unsigned short*)(ws + 200 * MB);      // ~1 MB bf16
    int*            deg   = (int*)(ws + 202 * MB);                 // 128 KB
    int*            off   = (int*)(ws + 202 * MB + 256 * 1024);    // 128 KB + 4
    int*            cur   = (int*)(ws + 202 * MB + 512 * 1024);    // 128 KB
    int*            elist = (int*)(ws + 202 * MB + 768 * 1024);    // 1 MB

    // weight transpose targets (bf16 [N][K])
    unsigned short* p = wt;
    unsigned short *wt_m0[L_], *wt_m1[L_], *wt_m2[L_], *wt_f0[L_], *wt_f1[L_];
    for (int l = 0; l < L_; ++l) {
        wt_m0[l] = p; p += 384 * 128;
        wt_m1[l] = p; p += 128 * 128;
        wt_m2[l] = p; p += 128 * 128;
        wt_f0[l] = p; p += 128 * 512;
        wt_f1[l] = p; p += 512 * 128;
    }
    unsigned short* wt_e0 = p; p += 384 * 128;
    unsigned short* wt_e1 = p; p += 128 * 128;
    unsigned short* wt_e2 = p; p += 128 * 128;

    // one batched transpose dispatch for all 13 live weight matrices
    TDA tda; int toff = 0, ti = 0;
    auto addT = [&](const float* s, unsigned short* d, int K, int N) {
        tda.v[ti++] = TD{s, d, toff, K, (N == 512 ? 9 : 7)};
        toff += K * N;
    };
    for (int l = 0; l < L_; ++l) {
        addT(msg_W0 + l * 384 * 128, wt_m0[l], 384, 128);
        addT(msg_W1 + l * 128 * 128, wt_m1[l], 128, 128);
        addT(msg_W2 + l * 128 * 128, wt_m2[l], 128, 128);
        addT(ff_W0  + l * 128 * 512, wt_f0[l], 128, 512);
        addT(ff_W1  + l * 512 * 128, wt_f1[l], 512, 128);
    }
    addT(e_W0, wt_e0, 384, 128);   // layer-0 edge update only (layer-1's is dead code)
    addT(e_W1, wt_e1, 128, 128);
    addT(e_W2, wt_e2, 128, 128);
    tda.total = toff;
    k_transpose_all<<<(toff + 255) / 256, 256, 0, stream>>>(tda);

    // fp32 -> bf16 activations (one dispatch)
    const int n4a = NNODES * 128 / 4, n4b = E_ * 128 / 4;
    k_cvt2<<<(n4a + n4b + 255) / 256, 256, 0, stream>>>(x, nodes, n4a, eat0, edgec, n4b);

    // CSR build (once — edge_index constant across layers)
    hipMemsetAsync(deg, 0, NNODES * sizeof(int), stream);
    k_deg<<<E_ / 256, 256, 0, stream>>>(ei, deg);
    k_scan<<<1, 1024, 0, stream>>>(deg, off);
    hipMemcpyAsync(cur, off, NNODES * sizeof(int), hipMemcpyDeviceToDevice, stream);
    k_bucket<<<E_ / 256, 256, 0, stream>>>(ei, cur, elist);

    const dim3 gE(E_ / 128, 1), gN64(NNODES / 64, 1), gN128(NNODES / 128, 1), gF0(NNODES / 128, 4);

    for (int l = 0; l < L_; ++l) {
        // --- message MLP + mean-aggregation + LN (CSR gather, no atomics) ---
        mlp_gemm<128, 384, 128, true,  true ><<<gE, 256, 0, stream>>>(nodes, edgec, ei, wt_m0[l], msg_b0 + l * 128, tmpA);
        mlp_gemm<128, 128, 128, false, true ><<<gE, 256, 0, stream>>>(tmpA, nullptr, nullptr, wt_m1[l], msg_b1 + l * 128, tmpB);
        mlp_gemm<128, 128, 128, false, false><<<gE, 256, 0, stream>>>(tmpB, nullptr, nullptr, wt_m2[l], msg_b2 + l * 128, tmpA);
        k_aggln<<<NNODES / 4, 256, 0, stream>>>(tmpA, off, elist, nodes, n0g + l * 128, n0b + l * 128, nodes);
        // --- feedforward + LN ---
        mlp_gemm<128, 128, 512, false, true ><<<gF0, 256, 0, stream>>>(nodes, nullptr, nullptr, wt_f0[l], ff_b0 + l * 512, ffh);
        mlp_gemm<64,  512, 128, false, false><<<gN64, 256, 0, stream>>>(ffh, nullptr, nullptr, wt_f1[l], ff_b1 + l * 128, ffo);
        if (l == L_ - 1) {
            k_ln<true ><<<NNODES / 4, 256, 0, stream>>>(nodes, ffo, n1g + l * 128, n1b + l * 128, d_out);
        } else {
            k_ln<false><<<NNODES / 4, 256, 0, stream>>>(nodes, ffo, n1g + l * 128, n1b + l * 128, nodes);
        }
        // --- edge update (only layer 0: the last layer's edge MLP never reaches the output) ---
        if (l == 0) {
            mlp_gemm<128, 384, 128, true,  true ><<<gE, 256, 0, stream>>>(nodes, edgec, ei, wt_e0, e_b0, tmpA);
            mlp_gemm<128, 128, 128, false, true ><<<gE, 256, 0, stream>>>(tmpA, nullptr, nullptr, wt_e1, e_b1, tmpB);
            mlp_gemm<128, 128, 128, false, false><<<gE, 256, 0, stream>>>(tmpB, nullptr, nullptr, wt_e2, e_b2, tmpA);
            k_ln<false><<<E_ / 4, 256, 0, stream>>>(edgec, tmpA, eng, enb, edgec);
        }
    }
}

// Round 5
// 536.443 us; speedup vs baseline: 2.6089x; 1.0792x over previous
//
#include <hip/hip_runtime.h>

#define E_      262144
#define NNODES  32768
#define L_      2

typedef __attribute__((ext_vector_type(8))) short  bf16x8;
typedef __attribute__((ext_vector_type(4))) float  f32x4;

typedef __attribute__((address_space(1))) const unsigned int gu32;
typedef __attribute__((address_space(3))) unsigned int       lu32;

__device__ __forceinline__ void gl16(const void* g, void* l) {
    // async global->LDS, 16B/lane; LDS dest = wave-uniform base + lane*16
    __builtin_amdgcn_global_load_lds((gu32*)g, (lu32*)l, 16, 0, 0);
}

__device__ __forceinline__ float bf2f(unsigned short u) {
    union { unsigned int i; float f; } v; v.i = ((unsigned int)u) << 16; return v.f;
}
__device__ __forceinline__ unsigned short f2bf(float f) {
    union { float f; unsigned int i; } v; v.f = f;
    unsigned int r = v.i + 0x7FFFu + ((v.i >> 16) & 1u);   // round-nearest-even
    return (unsigned short)(r >> 16);
}

// combined fp32->bf16 for nodes + edge_attr
__global__ __launch_bounds__(256)
void k_cvt2(const float* __restrict__ a, unsigned short* __restrict__ oa, int n4a,
            const float* __restrict__ b, unsigned short* __restrict__ ob, int n4b)
{
    int i = blockIdx.x * 256 + threadIdx.x;
    if (i < n4a) {
        float4 v = reinterpret_cast<const float4*>(a)[i];
        ushort4 o; o.x = f2bf(v.x); o.y = f2bf(v.y); o.z = f2bf(v.z); o.w = f2bf(v.w);
        reinterpret_cast<ushort4*>(oa)[i] = o;
    } else if (i < n4a + n4b) {
        int j = i - n4a;
        float4 v = reinterpret_cast<const float4*>(b)[j];
        ushort4 o; o.x = f2bf(v.x); o.y = f2bf(v.y); o.z = f2bf(v.z); o.w = f2bf(v.w);
        reinterpret_cast<ushort4*>(ob)[j] = o;
    }
}

// batched weight transpose: 13 matrices in one dispatch. [K][N] fp32 -> [N][K] bf16
struct TD  { const float* s; unsigned short* d; int off; int K; int nsh; };
struct TDA { TD v[13]; int total; };

__global__ __launch_bounds__(256)
void k_transpose_all(TDA t)
{
    int idx = blockIdx.x * 256 + threadIdx.x;
    if (idx >= t.total) return;
    int j = 0;
#pragma unroll
    for (int m = 1; m < 13; ++m) if (idx >= t.v[m].off) j = m;
    const TD& td = t.v[j];
    int local = idx - td.off;
    int k = local >> td.nsh;
    int n = local & ((1 << td.nsh) - 1);
    td.d[(size_t)n * td.K + k] = f2bf(td.s[local]);
}

// ---------------------------------------------------------------------------
// FUSED 3-stage edge MLP:  per block of 128 edges
//   X = concat(nodes[src], eattr, nodes[dst])          [128 x 384]  (gathered)
//   h1 = relu(X  @ W0 + b0)      -> LDS                [128 x 128]
//   h2 = relu(h1 @ W1 + b1)      -> LDS                [128 x 128]
//   m  =       h2 @ W2 + b2
//   LNEPI=0: out[e] = m (bf16)
//   LNEPI=1: out[e] = LayerNorm(eattr[e] + m) * g + b  (edge update, in-place ok)
// 4 waves as 2x2; each wave owns 64x64 (4x4 frags of 16x16, K-step 64).
// Staging via global_load_lds w=16, inverse-swizzled source (rule 21); LDS
// reads swizzled byte ^= (row&7)<<4 -> conflict-free-ish (2-way).
// LDS: S0 32KB (A-stage, later h2) + SB 16KB (W chunks, later LN scratch)
//      + H1 32KB = 80KB -> 2 blocks/CU.
// ---------------------------------------------------------------------------
template<bool LNEPI>
__global__ __launch_bounds__(256)
void fused_mlp3(const unsigned short* __restrict__ nodes,   // [NNODES][128]
                const unsigned short* __restrict__ eattr,   // [E][128]
                const int*            __restrict__ ei,      // [2][E]
                const unsigned short* __restrict__ W0T,     // [128][384]
                const unsigned short* __restrict__ W1T,     // [128][128]
                const unsigned short* __restrict__ W2T,     // [128][128]
                const float* __restrict__ b0, const float* __restrict__ b1,
                const float* __restrict__ b2,
                const float* __restrict__ g,  const float* __restrict__ bb,
                unsigned short* __restrict__ out)           // [E][128]
{
    __shared__ unsigned short S0[128 * 128];   // 32KB
    __shared__ unsigned short SB[128 * 64];    // 16KB
    __shared__ unsigned short H1[128 * 128];   // 32KB

    const int tid  = threadIdx.x;
    const int lane = tid & 63;
    const int w    = tid >> 6;
    const int wr   = w >> 1, wc = w & 1;
    const int m0   = blockIdx.x * 128;

    const int lrow = lane >> 3;                   // 0..7 row within an 8-row issue
    const int soff = ((lane & 7) ^ lrow) * 8;     // inverse-swizzled 16B slot (elems)

    char* S0c = (char*)S0;
    char* SBc = (char*)SB;
    char* H1c = (char*)H1;

    // gather pointers (4 issues of 8 rows per wave => 128 rows)
    const unsigned short *pS[4], *pD[4], *pE[4];
#pragma unroll
    for (int i = 0; i < 4; ++i) {
        int r = w * 32 + i * 8 + lrow;
        int e = m0 + r;
        pS[i] = nodes + (size_t)ei[e]      * 128 + soff;
        pD[i] = nodes + (size_t)ei[E_ + e] * 128 + soff;
        pE[i] = eattr + (size_t)e          * 128 + soff;
    }

    f32x4 acc[4][4];
    auto zacc = [&]() {
#pragma unroll
        for (int m = 0; m < 4; ++m)
#pragma unroll
            for (int n = 0; n < 4; ++n) acc[m][n] = (f32x4){0.f, 0.f, 0.f, 0.f};
    };

    // ---- MFMA tile step: A from LDS (stride abytes), B from SB ----
    auto mma = [&](const char* Ab, int abytes, int kbase) {
#pragma unroll
        for (int ks = 0; ks < 2; ++ks) {
            const int kb = (kbase + ks * 32) * 2 + (lane >> 4) * 16;
            bf16x8 a[4], b[4];
#pragma unroll
            for (int m = 0; m < 4; ++m) {
                int row = wr * 64 + m * 16 + (lane & 15);
                a[m] = *reinterpret_cast<const bf16x8*>(Ab + row * abytes + (kb ^ ((row & 7) << 4)));
            }
            const int kbb = ks * 64 + (lane >> 4) * 16;
#pragma unroll
            for (int n = 0; n < 4; ++n) {
                int row = wc * 64 + n * 16 + (lane & 15);
                b[n] = *reinterpret_cast<const bf16x8*>(SBc + row * 128 + (kbb ^ ((row & 7) << 4)));
            }
#pragma unroll
            for (int m = 0; m < 4; ++m)
#pragma unroll
                for (int n = 0; n < 4; ++n)
                    acc[m][n] = __builtin_amdgcn_mfma_f32_16x16x32_bf16(a[m], b[n], acc[m][n], 0, 0, 0);
        }
    };

    // ---- write activated acc -> LDS [128][128] bf16, swizzled slots ----
    auto towrite = [&](char* dst, const float* bias, bool relu) {
#pragma unroll
        for (int n = 0; n < 4; ++n) {
            int cg = wc * 64 + n * 16 + (lane & 15);
            float bi = bias[cg];
#pragma unroll
            for (int m = 0; m < 4; ++m) {
#pragma unroll
                for (int j = 0; j < 4; ++j) {
                    int rg = wr * 64 + m * 16 + (lane >> 4) * 4 + j;
                    float v = acc[m][n][j] + bi;
                    if (relu) v = fmaxf(v, 0.f);
                    *(unsigned short*)(dst + rg * 256 + ((2 * cg) ^ ((rg & 7) << 4))) = f2bf(v);
                }
            }
        }
    };

    // ================= phase 1: h1 = relu(X @ W0 + b0), K=384 =================
    zacc();
    for (int k0 = 0; k0 < 384; k0 += 64) {
#pragma unroll
        for (int i = 0; i < 4; ++i) {
            const unsigned short* pa = (k0 < 128 ? pS[i] : (k0 < 256 ? pE[i] : pD[i])) + (k0 & 64);
            gl16(pa, S0c + (w * 32 + i * 8) * 128);
        }
#pragma unroll
        for (int i = 0; i < 4; ++i)
            gl16(W0T + (size_t)(w * 32 + i * 8 + lrow) * 384 + k0 + soff,
                 SBc + (w * 32 + i * 8) * 128);
        __syncthreads();
        mma(S0c, 128, 0);
        __syncthreads();
    }
    towrite(H1c, b0, true);
    // ================= phase 2: h2 = relu(h1 @ W1 + b1), K=128 ================
    zacc();
#pragma unroll
    for (int k0 = 0; k0 < 128; k0 += 64) {
#pragma unroll
        for (int i = 0; i < 4; ++i)
            gl16(W1T + (size_t)(w * 32 + i * 8 + lrow) * 128 + k0 + soff,
                 SBc + (w * 32 + i * 8) * 128);
        __syncthreads();        // h1 writes + W1 chunk visible
        mma(H1c, 256, k0);
        __syncthreads();
    }
    towrite(S0c, b1, true);     // h2 into S0 (A-stage dead)
    // ================= phase 3: m = h2 @ W2 + b2, K=128 =======================
    zacc();
#pragma unroll
    for (int k0 = 0; k0 < 128; k0 += 64) {
#pragma unroll
        for (int i = 0; i < 4; ++i)
            gl16(W2T + (size_t)(w * 32 + i * 8 + lrow) * 128 + k0 + soff,
                 SBc + (w * 32 + i * 8) * 128);
        __syncthreads();
        mma(S0c, 256, k0);
        __syncthreads();
    }

    // ================= epilogue =================
    if (!LNEPI) {
#pragma unroll
        for (int n = 0; n < 4; ++n) {
            int cg = wc * 64 + n * 16 + (lane & 15);
            float bi = b2[cg];
#pragma unroll
            for (int m = 0; m < 4; ++m) {
                int rg = m0 + wr * 64 + m * 16 + (lane >> 4) * 4;
                unsigned short* cp = out + (size_t)rg * 128 + cg;
#pragma unroll
                for (int j = 0; j < 4; ++j)
                    cp[(size_t)j * 128] = f2bf(acc[m][n][j] + bi);
            }
        }
    } else {
        // residual + LayerNorm fused. vals = m + b2 + eattr (overwrite acc).
#pragma unroll
        for (int n = 0; n < 4; ++n) {
            int cg = wc * 64 + n * 16 + (lane & 15);
            float bi = b2[cg];
#pragma unroll
            for (int m = 0; m < 4; ++m) {
#pragma unroll
                for (int j = 0; j < 4; ++j) {
                    int rg = m0 + wr * 64 + m * 16 + (lane >> 4) * 4 + j;
                    acc[m][n][j] += bi + bf2f(eattr[(size_t)rg * 128 + cg]);
                }
            }
        }
        float* ps = (float*)SBc;          // [2][128] row sums   (SB dead)
        float* pq = ps + 256;             // [2][128] row sumsq
#pragma unroll
        for (int m = 0; m < 4; ++m) {
#pragma unroll
            for (int j = 0; j < 4; ++j) {
                float s = 0.f, q = 0.f;
#pragma unroll
                for (int n = 0; n < 4; ++n) {
                    float v = acc[m][n][j];
                    s += v; q += v * v;
                }
#pragma unroll
                for (int msk = 1; msk < 16; msk <<= 1) {
                    s += __shfl_xor(s, msk);
                    q += __shfl_xor(q, msk);
                }
                if ((lane & 15) == 0) {
                    int rl = wr * 64 + m * 16 + (lane >> 4) * 4 + j;
                    ps[wc * 128 + rl] = s;
                    pq[wc * 128 + rl] = q;
                }
            }
        }
        __syncthreads();
#pragma unroll
        for (int m = 0; m < 4; ++m) {
#pragma unroll
            for (int j = 0; j < 4; ++j) {
                int rl = wr * 64 + m * 16 + (lane >> 4) * 4 + j;
                float S = ps[rl] + ps[128 + rl];
                float Q = pq[rl] + pq[128 + rl];
                float mean = S * (1.f / 128.f);
                float var  = Q * (1.f / 128.f) - mean * mean;
                float rs   = rsqrtf(var + 1e-5f);
                int rg = m0 + rl;
#pragma unroll
                for (int n = 0; n < 4; ++n) {
                    int cg = wc * 64 + n * 16 + (lane & 15);
                    out[(size_t)rg * 128 + cg] =
                        f2bf((acc[m][n][j] - mean) * rs * g[cg] + bb[cg]);
                }
            }
        }
    }
}

// ---------------------------------------------------------------------------
// plain GEMM for the FF (non-gather): C = act(A @ W + bias)
// ---------------------------------------------------------------------------
template<int BM, int K, int NTOT, bool RELU>
__global__ __launch_bounds__(256)
void mlp_gemm(const unsigned short* __restrict__ Abase,
              const unsigned short* __restrict__ WT,      // [NTOT][K] bf16
              const float*          __restrict__ bias,    // [NTOT] fp32
              unsigned short*       __restrict__ C)       // [M][NTOT] bf16
{
    constexpr int MI = BM / 32;
    __shared__ unsigned short Alds[BM * 64];
    __shared__ unsigned short Blds[128 * 64];

    const int tid  = threadIdx.x;
    const int lane = tid & 63;
    const int w    = tid >> 6;
    const int wr   = w >> 1, wc = w & 1;
    const int m0   = blockIdx.x * BM;
    const int n0   = blockIdx.y * 128;

    const int lrow = lane >> 3;
    const int soff = ((lane & 7) ^ lrow) * 8;

    const unsigned short *pS[MI], *pB[4];
#pragma unroll
    for (int i = 0; i < MI; ++i)
        pS[i] = Abase + (size_t)(m0 + w * (BM / 4) + i * 8 + lrow) * K + soff;
#pragma unroll
    for (int i = 0; i < 4; ++i)
        pB[i] = WT + (size_t)(n0 + w * 32 + i * 8 + lrow) * K + soff;

    f32x4 acc[MI][4];
#pragma unroll
    for (int m = 0; m < MI; ++m)
#pragma unroll
        for (int n = 0; n < 4; ++n) acc[m][n] = (f32x4){0.f, 0.f, 0.f, 0.f};

#pragma unroll
    for (int k0 = 0; k0 < K; k0 += 64) {
#pragma unroll
        for (int i = 0; i < MI; ++i)
            gl16(pS[i] + k0, Alds + (w * (BM / 4) + i * 8) * 64);
#pragma unroll
        for (int i = 0; i < 4; ++i)
            gl16(pB[i] + k0, Blds + (w * 32 + i * 8) * 64);
        __syncthreads();

#pragma unroll
        for (int ks = 0; ks < 2; ++ks) {
            const int kb = ks * 64 + (lane >> 4) * 16;
            bf16x8 a[MI], b[4];
#pragma unroll
            for (int m = 0; m < MI; ++m) {
                int row = wr * (BM / 2) + m * 16 + (lane & 15);
                a[m] = *reinterpret_cast<const bf16x8*>(
                    (const char*)Alds + row * 128 + (kb ^ ((row & 7) << 4)));
            }
#pragma unroll
            for (int n = 0; n < 4; ++n) {
                int row = wc * 64 + n * 16 + (lane & 15);
                b[n] = *reinterpret_cast<const bf16x8*>(
                    (const char*)Blds + row * 128 + (kb ^ ((row & 7) << 4)));
            }
#pragma unroll
            for (int m = 0; m < MI; ++m)
#pragma unroll
                for (int n = 0; n < 4; ++n)
                    acc[m][n] = __builtin_amdgcn_mfma_f32_16x16x32_bf16(a[m], b[n], acc[m][n], 0, 0, 0);
        }
        __syncthreads();
    }

#pragma unroll
    for (int n = 0; n < 4; ++n) {
        int colg = n0 + wc * 64 + n * 16 + (lane & 15);
        float bi = bias[colg];
#pragma unroll
        for (int m = 0; m < MI; ++m) {
            int rowg = m0 + wr * (BM / 2) + m * 16 + (lane >> 4) * 4;
            unsigned short* cp = C + (size_t)rowg * NTOT + colg;
#pragma unroll
            for (int j = 0; j < 4; ++j) {
                float r = acc[m][n][j] + bi;
                if (RELU) r = fmaxf(r, 0.f);
                cp[(size_t)j * NTOT] = f2bf(r);
            }
        }
    }
}

__global__ __launch_bounds__(256)
void k_deg(const int* __restrict__ ei, int* __restrict__ deg)
{
    int e = blockIdx.x * 256 + threadIdx.x;
    atomicAdd(&deg[ei[E_ + e]], 1);
}

// exclusive scan of deg[32768] -> off[32769]
__global__ __launch_bounds__(1024)
void k_scan(const int* __restrict__ deg, int* __restrict__ off)
{
    __shared__ int part[1024];
    const int t = threadIdx.x;
    const int base = t * 32;
    int loc[32];
    int s = 0;
#pragma unroll
    for (int i = 0; i < 32; ++i) { loc[i] = s; s += deg[base + i]; }
    part[t] = s;
    __syncthreads();
    for (int d = 1; d < 1024; d <<= 1) {
        int v = (t >= d) ? part[t - d] : 0;
        __syncthreads();
        part[t] += v;
        __syncthreads();
    }
    const int pre = (t == 0) ? 0 : part[t - 1];
#pragma unroll
    for (int i = 0; i < 32; ++i) off[base + i] = pre + loc[i];
    if (t == 1023) off[NNODES] = pre + s;
}

__global__ __launch_bounds__(256)
void k_bucket(const int* __restrict__ ei, int* __restrict__ cursor, int* __restrict__ elist)
{
    int e = blockIdx.x * 256 + threadIdx.x;
    int d = ei[E_ + e];
    int pos = atomicAdd(&cursor[d], 1);
    elist[pos] = e;
}

// Fused: agg = mean_{e in CSR[v]} m[e];  out = LN(nodes_in[v] + agg).
__global__ __launch_bounds__(256)
void k_aggln(const unsigned short* __restrict__ m,
             const int* __restrict__ off, const int* __restrict__ elist,
             const unsigned short* __restrict__ nodes_in,
             const float* __restrict__ g, const float* __restrict__ bb,
             unsigned short* __restrict__ nodes_out)
{
    const int v    = blockIdx.x * 4 + (threadIdx.x >> 6);
    const int lane = threadIdx.x & 63;
    const int c    = lane * 2;
    const int beg  = off[v], end = off[v + 1];

    float a0 = 0.f, a1 = 0.f;
    for (int i = beg; i < end; ++i) {
        int e = elist[i];
        unsigned int u = *reinterpret_cast<const unsigned int*>(m + (size_t)e * 128 + c);
        a0 += bf2f((unsigned short)(u & 0xffffu));
        a1 += bf2f((unsigned short)(u >> 16));
    }
    const float inv = 1.f / fmaxf((float)(end - beg), 1.f);
    const size_t o = (size_t)v * 128 + c;
    float x0 = bf2f(nodes_in[o])     + a0 * inv;
    float x1 = bf2f(nodes_in[o + 1]) + a1 * inv;

    float s = x0 + x1, sq = x0 * x0 + x1 * x1;
#pragma unroll
    for (int mm = 1; mm < 64; mm <<= 1) { s += __shfl_xor(s, mm); sq += __shfl_xor(sq, mm); }
    float mean = s * (1.f / 128.f);
    float var  = sq * (1.f / 128.f) - mean * mean;
    float rs   = rsqrtf(var + 1e-5f);
    nodes_out[o]     = f2bf((x0 - mean) * rs * g[c]     + bb[c]);
    nodes_out[o + 1] = f2bf((x1 - mean) * rs * g[c + 1] + bb[c + 1]);
}

// Fused residual + LayerNorm (bf16 residual). F32OUT: fp32 final output.
template<bool F32OUT>
__global__ __launch_bounds__(256)
void k_ln(const unsigned short* __restrict__ base,
          const unsigned short* __restrict__ res,
          const float* __restrict__ g, const float* __restrict__ bb,
          void* __restrict__ outp)
{
    int row  = blockIdx.x * 4 + (threadIdx.x >> 6);
    int lane = threadIdx.x & 63;
    int c    = lane * 2;
    size_t off = (size_t)row * 128 + c;

    float x0 = bf2f(base[off])     + bf2f(res[off]);
    float x1 = bf2f(base[off + 1]) + bf2f(res[off + 1]);
    float s = x0 + x1, sq = x0 * x0 + x1 * x1;
#pragma unroll
    for (int m = 1; m < 64; m <<= 1) { s += __shfl_xor(s, m); sq += __shfl_xor(sq, m); }
    float mean = s * (1.f / 128.f);
    float var  = sq * (1.f / 128.f) - mean * mean;
    float rs   = rsqrtf(var + 1e-5f);
    float y0 = (x0 - mean) * rs * g[c]     + bb[c];
    float y1 = (x1 - mean) * rs * g[c + 1] + bb[c + 1];
    if (F32OUT) {
        ((float*)outp)[off]     = y0;
        ((float*)outp)[off + 1] = y1;
    } else {
        ((unsigned short*)outp)[off]     = f2bf(y0);
        ((unsigned short*)outp)[off + 1] = f2bf(y1);
    }
}

// ---------------------------------------------------------------------------
extern "C" void kernel_launch(void* const* d_in, const int* in_sizes, int n_in,
                              void* d_out, int out_size, void* d_ws, size_t ws_size,
                              hipStream_t stream)
{
    const float* x      = (const float*)d_in[0];
    const int*   ei     = (const int*)d_in[1];
    const float* eat0   = (const float*)d_in[2];
    const float* msg_W0 = (const float*)d_in[3];
    const float* msg_b0 = (const float*)d_in[4];
    const float* msg_W1 = (const float*)d_in[5];
    const float* msg_b1 = (const float*)d_in[6];
    const float* msg_W2 = (const float*)d_in[7];
    const float* msg_b2 = (const float*)d_in[8];
    const float* n0g    = (const float*)d_in[9];
    const float* n0b    = (const float*)d_in[10];
    const float* ff_W0  = (const float*)d_in[11];
    const float* ff_b0  = (const float*)d_in[12];
    const float* ff_W1  = (const float*)d_in[13];
    const float* ff_b1  = (const float*)d_in[14];
    const float* n1g    = (const float*)d_in[15];
    const float* n1b    = (const float*)d_in[16];
    const float* e_W0   = (const float*)d_in[17];
    const float* e_b0   = (const float*)d_in[18];
    const float* e_W1   = (const float*)d_in[19];
    const float* e_b1   = (const float*)d_in[20];
    const float* e_W2   = (const float*)d_in[21];
    const float* e_b2   = (const float*)d_in[22];
    const float* eng    = (const float*)d_in[23];
    const float* enb    = (const float*)d_in[24];

    char* ws = (char*)d_ws;
    const size_t MB = (size_t)1 << 20;
    unsigned short* nodes = (unsigned short*)(ws);                 // 8 MB bf16
    unsigned short* edgec = (unsigned short*)(ws + 8 * MB);        // 64 MB bf16
    unsigned short* tmpA  = (unsigned short*)(ws + 72 * MB);       // 64 MB (msg out m)
    unsigned short* ffh   = (unsigned short*)(ws + 136 * MB);      // 32 MB (FF hidden)
    unsigned short* ffo   = tmpA;                                  // alias (phase-disjoint)
    unsigned short* wt    = (unsigned short*)(ws + 200 * MB);      // ~1 MB bf16
    int*            deg   = (int*)(ws + 202 * MB);                 // 128 KB
    int*            off   = (int*)(ws + 202 * MB + 256 * 1024);    // 128 KB + 4
    int*            cur   = (int*)(ws + 202 * MB + 512 * 1024);    // 128 KB
    int*            elist = (int*)(ws + 202 * MB + 768 * 1024);    // 1 MB

    // weight transpose targets (bf16 [N][K])
    unsigned short* p = wt;
    unsigned short *wt_m0[L_], *wt_m1[L_], *wt_m2[L_], *wt_f0[L_], *wt_f1[L_];
    for (int l = 0; l < L_; ++l) {
        wt_m0[l] = p; p += 384 * 128;
        wt_m1[l] = p; p += 128 * 128;
        wt_m2[l] = p; p += 128 * 128;
        wt_f0[l] = p; p += 128 * 512;
        wt_f1[l] = p; p += 512 * 128;
    }
    unsigned short* wt_e0 = p; p += 384 * 128;
    unsigned short* wt_e1 = p; p += 128 * 128;
    unsigned short* wt_e2 = p; p += 128 * 128;

    TDA tda; int toff = 0, ti = 0;
    auto addT = [&](const float* s, unsigned short* d, int K, int N) {
        tda.v[ti++] = TD{s, d, toff, K, (N == 512 ? 9 : 7)};
        toff += K * N;
    };
    for (int l = 0; l < L_; ++l) {
        addT(msg_W0 + l * 384 * 128, wt_m0[l], 384, 128);
        addT(msg_W1 + l * 128 * 128, wt_m1[l], 128, 128);
        addT(msg_W2 + l * 128 * 128, wt_m2[l], 128, 128);
        addT(ff_W0  + l * 128 * 512, wt_f0[l], 128, 512);
        addT(ff_W1  + l * 512 * 128, wt_f1[l], 512, 128);
    }
    addT(e_W0, wt_e0, 384, 128);   // layer-0 edge update only (layer-1's is dead code)
    addT(e_W1, wt_e1, 128, 128);
    addT(e_W2, wt_e2, 128, 128);
    tda.total = toff;
    k_transpose_all<<<(toff + 255) / 256, 256, 0, stream>>>(tda);

    const int n4a = NNODES * 128 / 4, n4b = E_ * 128 / 4;
    k_cvt2<<<(n4a + n4b + 255) / 256, 256, 0, stream>>>(x, nodes, n4a, eat0, edgec, n4b);

    // CSR build (once — edge_index constant across layers)
    hipMemsetAsync(deg, 0, NNODES * sizeof(int), stream);
    k_deg<<<E_ / 256, 256, 0, stream>>>(ei, deg);
    k_scan<<<1, 1024, 0, stream>>>(deg, off);
    hipMemcpyAsync(cur, off, NNODES * sizeof(int), hipMemcpyDeviceToDevice, stream);
    k_bucket<<<E_ / 256, 256, 0, stream>>>(ei, cur, elist);

    const dim3 gE(E_ / 128, 1), gN64(NNODES / 64, 1), gF0(NNODES / 128, 4);

    for (int l = 0; l < L_; ++l) {
        // --- fused message MLP (3 GEMMs in one kernel) -> m ---
        fused_mlp3<false><<<gE, 256, 0, stream>>>(nodes, edgec, ei,
            wt_m0[l], wt_m1[l], wt_m2[l],
            msg_b0 + l * 128, msg_b1 + l * 128, msg_b2 + l * 128,
            nullptr, nullptr, tmpA);
        k_aggln<<<NNODES / 4, 256, 0, stream>>>(tmpA, off, elist, nodes,
            n0g + l * 128, n0b + l * 128, nodes);
        // --- feedforward + LN ---
        mlp_gemm<128, 128, 512, true ><<<gF0, 256, 0, stream>>>(nodes, wt_f0[l], ff_b0 + l * 512, ffh);
        mlp_gemm<64,  512, 128, false><<<gN64, 256, 0, stream>>>(ffh, wt_f1[l], ff_b1 + l * 128, ffo);
        if (l == L_ - 1) {
            k_ln<true ><<<NNODES / 4, 256, 0, stream>>>(nodes, ffo, n1g + l * 128, n1b + l * 128, d_out);
        } else {
            k_ln<false><<<NNODES / 4, 256, 0, stream>>>(nodes, ffo, n1g + l * 128, n1b + l * 128, nodes);
        }
        // --- fused edge update incl. residual+LN (only layer 0; layer-1's is dead) ---
        if (l == 0) {
            fused_mlp3<true><<<gE, 256, 0, stream>>>(nodes, edgec, ei,
                wt_e0, wt_e1, wt_e2, e_b0, e_b1, e_b2, eng, enb, edgec);
        }
    }
}

// Round 6
// 462.810 us; speedup vs baseline: 3.0239x; 1.1591x over previous
//
#include <hip/hip_runtime.h>

#define E_      262144
#define NNODES  32768
#define L_      2

typedef __attribute__((ext_vector_type(8))) short  bf16x8;
typedef __attribute__((ext_vector_type(4))) float  f32x4;

typedef __attribute__((address_space(1))) const unsigned int gu32;
typedef __attribute__((address_space(3))) unsigned int       lu32;

__device__ __forceinline__ void gl16(const void* g, void* l) {
    // async global->LDS, 16B/lane; LDS dest = wave-uniform base + lane*16
    __builtin_amdgcn_global_load_lds((gu32*)g, (lu32*)l, 16, 0, 0);
}

__device__ __forceinline__ float bf2f(unsigned short u) {
    union { unsigned int i; float f; } v; v.i = ((unsigned int)u) << 16; return v.f;
}
__device__ __forceinline__ unsigned short f2bf(float f) {
    union { float f; unsigned int i; } v; v.f = f;
    unsigned int r = v.i + 0x7FFFu + ((v.i >> 16) & 1u);   // round-nearest-even
    return (unsigned short)(r >> 16);
}

// combined fp32->bf16 for nodes + edge_attr
__global__ __launch_bounds__(256)
void k_cvt2(const float* __restrict__ a, unsigned short* __restrict__ oa, int n4a,
            const float* __restrict__ b, unsigned short* __restrict__ ob, int n4b)
{
    int i = blockIdx.x * 256 + threadIdx.x;
    if (i < n4a) {
        float4 v = reinterpret_cast<const float4*>(a)[i];
        ushort4 o; o.x = f2bf(v.x); o.y = f2bf(v.y); o.z = f2bf(v.z); o.w = f2bf(v.w);
        reinterpret_cast<ushort4*>(oa)[i] = o;
    } else if (i < n4a + n4b) {
        int j = i - n4a;
        float4 v = reinterpret_cast<const float4*>(b)[j];
        ushort4 o; o.x = f2bf(v.x); o.y = f2bf(v.y); o.z = f2bf(v.z); o.w = f2bf(v.w);
        reinterpret_cast<ushort4*>(ob)[j] = o;
    }
}

// batched weight transpose: 13 matrices in one dispatch. [K][N] fp32 -> [N][K] bf16
struct TD  { const float* s; unsigned short* d; int off; int K; int nsh; };
struct TDA { TD v[13]; int total; };

__global__ __launch_bounds__(256)
void k_transpose_all(TDA t)
{
    int idx = blockIdx.x * 256 + threadIdx.x;
    if (idx >= t.total) return;
    int j = 0;
#pragma unroll
    for (int m = 1; m < 13; ++m) if (idx >= t.v[m].off) j = m;
    const TD& td = t.v[j];
    int local = idx - td.off;
    int k = local >> td.nsh;
    int n = local & ((1 << td.nsh) - 1);
    td.d[(size_t)n * td.K + k] = f2bf(td.s[local]);
}

// ---------------------------------------------------------------------------
// FUSED 3-stage edge MLP, BM=64 rows/block (occupancy-first: 40KB LDS ->
// 4 blocks/CU; __launch_bounds__(256,4) caps VGPR<=128 -> 16 waves/CU so
// other blocks' waves hide each block's barrier drains).
//   X  = concat(nodes[src], eattr, nodes[dst])      [64 x 384] (gathered)
//   h1 = relu(X  @ W0 + b0) -> H                    [64 x 128]
//   h2 = relu(h1 @ W1 + b1) -> H (overwrite: safe, last h1 read precedes
//                                 the loop-final barrier)
//   m  =       h2 @ W2 + b2
//   LNEPI=0: out[e] = m;  LNEPI=1: out[e] = LN(eattr[e] + m) * g + b
// 4 waves 2x2: wave = 32 rows x 64 cols = 2x4 frags of 16x16, K-step 64.
// global_load_lds w=16, inverse-swizzled source (rule 21), swizzled LDS reads.
// ---------------------------------------------------------------------------
template<bool LNEPI>
__global__ __launch_bounds__(256, 4)
void fused_mlp3(const unsigned short* __restrict__ nodes,   // [NNODES][128]
                const unsigned short* __restrict__ eattr,   // [E][128]
                const int*            __restrict__ ei,      // [2][E]
                const unsigned short* __restrict__ W0T,     // [128][384]
                const unsigned short* __restrict__ W1T,     // [128][128]
                const unsigned short* __restrict__ W2T,     // [128][128]
                const float* __restrict__ b0, const float* __restrict__ b1,
                const float* __restrict__ b2,
                const float* __restrict__ g,  const float* __restrict__ bb,
                unsigned short* __restrict__ out)           // [E][128]
{
    __shared__ unsigned short S0[64 * 64];     //  8KB A-stage
    __shared__ unsigned short SB[128 * 64];    // 16KB W-stage (later LN scratch)
    __shared__ unsigned short H [64 * 128];    // 16KB h1 then h2

    const int tid  = threadIdx.x;
    const int lane = tid & 63;
    const int w    = tid >> 6;
    const int wr   = w >> 1, wc = w & 1;
    const int m0   = blockIdx.x * 64;

    const int lrow = lane >> 3;                   // 0..7 row within an 8-row issue
    const int soff = ((lane & 7) ^ lrow) * 8;     // inverse-swizzled 16B slot (elems)

    char* S0c = (char*)S0;
    char* SBc = (char*)SB;
    char* Hc  = (char*)H;

    // gather pointers: 2 issues of 8 rows per wave => 64 rows
    const unsigned short *pS[2], *pD[2], *pE[2];
#pragma unroll
    for (int i = 0; i < 2; ++i) {
        int r = w * 16 + i * 8 + lrow;
        int e = m0 + r;
        pS[i] = nodes + (size_t)ei[e]      * 128 + soff;
        pD[i] = nodes + (size_t)ei[E_ + e] * 128 + soff;
        pE[i] = eattr + (size_t)e          * 128 + soff;
    }

    f32x4 acc[2][4];
    auto zacc = [&]() {
#pragma unroll
        for (int m = 0; m < 2; ++m)
#pragma unroll
            for (int n = 0; n < 4; ++n) acc[m][n] = (f32x4){0.f, 0.f, 0.f, 0.f};
    };

    // ---- MFMA tile step: A from LDS (row stride abytes), B from SB ----
    auto mma = [&](const char* Ab, int abytes, int kbase) {
#pragma unroll
        for (int ks = 0; ks < 2; ++ks) {
            const int kb = (kbase + ks * 32) * 2 + (lane >> 4) * 16;
            bf16x8 a[2], b[4];
#pragma unroll
            for (int m = 0; m < 2; ++m) {
                int row = wr * 32 + m * 16 + (lane & 15);
                a[m] = *reinterpret_cast<const bf16x8*>(Ab + row * abytes + (kb ^ ((row & 7) << 4)));
            }
            const int kbb = ks * 64 + (lane >> 4) * 16;
#pragma unroll
            for (int n = 0; n < 4; ++n) {
                int row = wc * 64 + n * 16 + (lane & 15);
                b[n] = *reinterpret_cast<const bf16x8*>(SBc + row * 128 + (kbb ^ ((row & 7) << 4)));
            }
#pragma unroll
            for (int m = 0; m < 2; ++m)
#pragma unroll
                for (int n = 0; n < 4; ++n)
                    acc[m][n] = __builtin_amdgcn_mfma_f32_16x16x32_bf16(a[m], b[n], acc[m][n], 0, 0, 0);
        }
    };

    // ---- write activated acc -> H [64][128] bf16, swizzled slots ----
    auto towrite = [&](const float* bias) {
#pragma unroll
        for (int n = 0; n < 4; ++n) {
            int cg = wc * 64 + n * 16 + (lane & 15);
            float bi = bias[cg];
#pragma unroll
            for (int m = 0; m < 2; ++m) {
#pragma unroll
                for (int j = 0; j < 4; ++j) {
                    int rg = wr * 32 + m * 16 + (lane >> 4) * 4 + j;
                    float v = fmaxf(acc[m][n][j] + bi, 0.f);
                    *(unsigned short*)(Hc + rg * 256 + ((2 * cg) ^ ((rg & 7) << 4))) = f2bf(v);
                }
            }
        }
    };

    // ================= phase 1: h1 = relu(X @ W0 + b0), K=384 =================
    zacc();
    for (int k0 = 0; k0 < 384; k0 += 64) {
#pragma unroll
        for (int i = 0; i < 2; ++i) {
            const unsigned short* pa = (k0 < 128 ? pS[i] : (k0 < 256 ? pE[i] : pD[i])) + (k0 & 64);
            gl16(pa, S0c + (w * 16 + i * 8) * 128);
        }
#pragma unroll
        for (int i = 0; i < 4; ++i)
            gl16(W0T + (size_t)(w * 32 + i * 8 + lrow) * 384 + k0 + soff,
                 SBc + (w * 32 + i * 8) * 128);
        __syncthreads();
        mma(S0c, 128, 0);
        __syncthreads();
    }
    towrite(b0);
    // ================= phase 2: h2 = relu(h1 @ W1 + b1), K=128 ================
    zacc();
#pragma unroll
    for (int k0 = 0; k0 < 128; k0 += 64) {
#pragma unroll
        for (int i = 0; i < 4; ++i)
            gl16(W1T + (size_t)(w * 32 + i * 8 + lrow) * 128 + k0 + soff,
                 SBc + (w * 32 + i * 8) * 128);
        __syncthreads();        // h1 writes + W1 chunk visible
        mma(Hc, 256, k0);
        __syncthreads();
    }
    towrite(b1);                // h2 over h1: all h1 reads completed at loop-final barrier
    // ================= phase 3: m = h2 @ W2 + b2, K=128 =======================
    zacc();
#pragma unroll
    for (int k0 = 0; k0 < 128; k0 += 64) {
#pragma unroll
        for (int i = 0; i < 4; ++i)
            gl16(W2T + (size_t)(w * 32 + i * 8 + lrow) * 128 + k0 + soff,
                 SBc + (w * 32 + i * 8) * 128);
        __syncthreads();        // h2 writes + W2 chunk visible
        mma(Hc, 256, k0);
        __syncthreads();
    }

    // ================= epilogue =================
    if (!LNEPI) {
#pragma unroll
        for (int n = 0; n < 4; ++n) {
            int cg = wc * 64 + n * 16 + (lane & 15);
            float bi = b2[cg];
#pragma unroll
            for (int m = 0; m < 2; ++m) {
                int rg = m0 + wr * 32 + m * 16 + (lane >> 4) * 4;
                unsigned short* cp = out + (size_t)rg * 128 + cg;
#pragma unroll
                for (int j = 0; j < 4; ++j)
                    cp[(size_t)j * 128] = f2bf(acc[m][n][j] + bi);
            }
        }
    } else {
        // residual + LayerNorm fused. vals = m + b2 + eattr.
#pragma unroll
        for (int n = 0; n < 4; ++n) {
            int cg = wc * 64 + n * 16 + (lane & 15);
            float bi = b2[cg];
#pragma unroll
            for (int m = 0; m < 2; ++m) {
#pragma unroll
                for (int j = 0; j < 4; ++j) {
                    int rg = m0 + wr * 32 + m * 16 + (lane >> 4) * 4 + j;
                    acc[m][n][j] += bi + bf2f(eattr[(size_t)rg * 128 + cg]);
                }
            }
        }
        float* ps = (float*)SBc;          // [2][64] row sums   (SB dead)
        float* pq = ps + 128;             // [2][64] row sumsq
#pragma unroll
        for (int m = 0; m < 2; ++m) {
#pragma unroll
            for (int j = 0; j < 4; ++j) {
                float s = 0.f, q = 0.f;
#pragma unroll
                for (int n = 0; n < 4; ++n) {
                    float v = acc[m][n][j];
                    s += v; q += v * v;
                }
#pragma unroll
                for (int msk = 1; msk < 16; msk <<= 1) {
                    s += __shfl_xor(s, msk);
                    q += __shfl_xor(q, msk);
                }
                if ((lane & 15) == 0) {
                    int rl = wr * 32 + m * 16 + (lane >> 4) * 4 + j;
                    ps[wc * 64 + rl] = s;
                    pq[wc * 64 + rl] = q;
                }
            }
        }
        __syncthreads();
#pragma unroll
        for (int m = 0; m < 2; ++m) {
#pragma unroll
            for (int j = 0; j < 4; ++j) {
                int rl = wr * 32 + m * 16 + (lane >> 4) * 4 + j;
                float S = ps[rl] + ps[64 + rl];
                float Q = pq[rl] + pq[64 + rl];
                float mean = S * (1.f / 128.f);
                float var  = Q * (1.f / 128.f) - mean * mean;
                float rs   = rsqrtf(var + 1e-5f);
                int rg = m0 + rl;
#pragma unroll
                for (int n = 0; n < 4; ++n) {
                    int cg = wc * 64 + n * 16 + (lane & 15);
                    out[(size_t)rg * 128 + cg] =
                        f2bf((acc[m][n][j] - mean) * rs * g[cg] + bb[cg]);
                }
            }
        }
    }
}

// ---------------------------------------------------------------------------
// plain GEMM for the FF (non-gather): C = act(A @ W + bias)
// ---------------------------------------------------------------------------
template<int BM, int K, int NTOT, bool RELU>
__global__ __launch_bounds__(256)
void mlp_gemm(const unsigned short* __restrict__ Abase,
              const unsigned short* __restrict__ WT,      // [NTOT][K] bf16
              const float*          __restrict__ bias,    // [NTOT] fp32
              unsigned short*       __restrict__ C)       // [M][NTOT] bf16
{
    constexpr int MI = BM / 32;
    __shared__ unsigned short Alds[BM * 64];
    __shared__ unsigned short Blds[128 * 64];

    const int tid  = threadIdx.x;
    const int lane = tid & 63;
    const int w    = tid >> 6;
    const int wr   = w >> 1, wc = w & 1;
    const int m0   = blockIdx.x * BM;
    const int n0   = blockIdx.y * 128;

    const int lrow = lane >> 3;
    const int soff = ((lane & 7) ^ lrow) * 8;

    const unsigned short *pS[MI], *pB[4];
#pragma unroll
    for (int i = 0; i < MI; ++i)
        pS[i] = Abase + (size_t)(m0 + w * (BM / 4) + i * 8 + lrow) * K + soff;
#pragma unroll
    for (int i = 0; i < 4; ++i)
        pB[i] = WT + (size_t)(n0 + w * 32 + i * 8 + lrow) * K + soff;

    f32x4 acc[MI][4];
#pragma unroll
    for (int m = 0; m < MI; ++m)
#pragma unroll
        for (int n = 0; n < 4; ++n) acc[m][n] = (f32x4){0.f, 0.f, 0.f, 0.f};

#pragma unroll
    for (int k0 = 0; k0 < K; k0 += 64) {
#pragma unroll
        for (int i = 0; i < MI; ++i)
            gl16(pS[i] + k0, Alds + (w * (BM / 4) + i * 8) * 64);
#pragma unroll
        for (int i = 0; i < 4; ++i)
            gl16(pB[i] + k0, Blds + (w * 32 + i * 8) * 64);
        __syncthreads();

#pragma unroll
        for (int ks = 0; ks < 2; ++ks) {
            const int kb = ks * 64 + (lane >> 4) * 16;
            bf16x8 a[MI], b[4];
#pragma unroll
            for (int m = 0; m < MI; ++m) {
                int row = wr * (BM / 2) + m * 16 + (lane & 15);
                a[m] = *reinterpret_cast<const bf16x8*>(
                    (const char*)Alds + row * 128 + (kb ^ ((row & 7) << 4)));
            }
#pragma unroll
            for (int n = 0; n < 4; ++n) {
                int row = wc * 64 + n * 16 + (lane & 15);
                b[n] = *reinterpret_cast<const bf16x8*>(
                    (const char*)Blds + row * 128 + (kb ^ ((row & 7) << 4)));
            }
#pragma unroll
            for (int m = 0; m < MI; ++m)
#pragma unroll
                for (int n = 0; n < 4; ++n)
                    acc[m][n] = __builtin_amdgcn_mfma_f32_16x16x32_bf16(a[m], b[n], acc[m][n], 0, 0, 0);
        }
        __syncthreads();
    }

#pragma unroll
    for (int n = 0; n < 4; ++n) {
        int colg = n0 + wc * 64 + n * 16 + (lane & 15);
        float bi = bias[colg];
#pragma unroll
        for (int m = 0; m < MI; ++m) {
            int rowg = m0 + wr * (BM / 2) + m * 16 + (lane >> 4) * 4;
            unsigned short* cp = C + (size_t)rowg * NTOT + colg;
#pragma unroll
            for (int j = 0; j < 4; ++j) {
                float r = acc[m][n][j] + bi;
                if (RELU) r = fmaxf(r, 0.f);
                cp[(size_t)j * NTOT] = f2bf(r);
            }
        }
    }
}

__global__ __launch_bounds__(256)
void k_deg(const int* __restrict__ ei, int* __restrict__ deg)
{
    int e = blockIdx.x * 256 + threadIdx.x;
    atomicAdd(&deg[ei[E_ + e]], 1);
}

// exclusive scan of deg[32768] -> off[32769]
__global__ __launch_bounds__(1024)
void k_scan(const int* __restrict__ deg, int* __restrict__ off)
{
    __shared__ int part[1024];
    const int t = threadIdx.x;
    const int base = t * 32;
    int loc[32];
    int s = 0;
#pragma unroll
    for (int i = 0; i < 32; ++i) { loc[i] = s; s += deg[base + i]; }
    part[t] = s;
    __syncthreads();
    for (int d = 1; d < 1024; d <<= 1) {
        int v = (t >= d) ? part[t - d] : 0;
        __syncthreads();
        part[t] += v;
        __syncthreads();
    }
    const int pre = (t == 0) ? 0 : part[t - 1];
#pragma unroll
    for (int i = 0; i < 32; ++i) off[base + i] = pre + loc[i];
    if (t == 1023) off[NNODES] = pre + s;
}

__global__ __launch_bounds__(256)
void k_bucket(const int* __restrict__ ei, int* __restrict__ cursor, int* __restrict__ elist)
{
    int e = blockIdx.x * 256 + threadIdx.x;
    int d = ei[E_ + e];
    int pos = atomicAdd(&cursor[d], 1);
    elist[pos] = e;
}

// Fused: agg = mean_{e in CSR[v]} m[e];  out = LN(nodes_in[v] + agg).
__global__ __launch_bounds__(256)
void k_aggln(const unsigned short* __restrict__ m,
             const int* __restrict__ off, const int* __restrict__ elist,
             const unsigned short* __restrict__ nodes_in,
             const float* __restrict__ g, const float* __restrict__ bb,
             unsigned short* __restrict__ nodes_out)
{
    const int v    = blockIdx.x * 4 + (threadIdx.x >> 6);
    const int lane = threadIdx.x & 63;
    const int c    = lane * 2;
    const int beg  = off[v], end = off[v + 1];

    float a0 = 0.f, a1 = 0.f;
    for (int i = beg; i < end; ++i) {
        int e = elist[i];
        unsigned int u = *reinterpret_cast<const unsigned int*>(m + (size_t)e * 128 + c);
        a0 += bf2f((unsigned short)(u & 0xffffu));
        a1 += bf2f((unsigned short)(u >> 16));
    }
    const float inv = 1.f / fmaxf((float)(end - beg), 1.f);
    const size_t o = (size_t)v * 128 + c;
    float x0 = bf2f(nodes_in[o])     + a0 * inv;
    float x1 = bf2f(nodes_in[o + 1]) + a1 * inv;

    float s = x0 + x1, sq = x0 * x0 + x1 * x1;
#pragma unroll
    for (int mm = 1; mm < 64; mm <<= 1) { s += __shfl_xor(s, mm); sq += __shfl_xor(sq, mm); }
    float mean = s * (1.f / 128.f);
    float var  = sq * (1.f / 128.f) - mean * mean;
    float rs   = rsqrtf(var + 1e-5f);
    nodes_out[o]     = f2bf((x0 - mean) * rs * g[c]     + bb[c]);
    nodes_out[o + 1] = f2bf((x1 - mean) * rs * g[c + 1] + bb[c + 1]);
}

// Fused residual + LayerNorm (bf16 residual). F32OUT: fp32 final output.
template<bool F32OUT>
__global__ __launch_bounds__(256)
void k_ln(const unsigned short* __restrict__ base,
          const unsigned short* __restrict__ res,
          const float* __restrict__ g, const float* __restrict__ bb,
          void* __restrict__ outp)
{
    int row  = blockIdx.x * 4 + (threadIdx.x >> 6);
    int lane = threadIdx.x & 63;
    int c    = lane * 2;
    size_t off = (size_t)row * 128 + c;

    float x0 = bf2f(base[off])     + bf2f(res[off]);
    float x1 = bf2f(base[off + 1]) + bf2f(res[off + 1]);
    float s = x0 + x1, sq = x0 * x0 + x1 * x1;
#pragma unroll
    for (int m = 1; m < 64; m <<= 1) { s += __shfl_xor(s, m); sq += __shfl_xor(sq, m); }
    float mean = s * (1.f / 128.f);
    float var  = sq * (1.f / 128.f) - mean * mean;
    float rs   = rsqrtf(var + 1e-5f);
    float y0 = (x0 - mean) * rs * g[c]     + bb[c];
    float y1 = (x1 - mean) * rs * g[c + 1] + bb[c + 1];
    if (F32OUT) {
        ((float*)outp)[off]     = y0;
        ((float*)outp)[off + 1] = y1;
    } else {
        ((unsigned short*)outp)[off]     = f2bf(y0);
        ((unsigned short*)outp)[off + 1] = f2bf(y1);
    }
}

// ---------------------------------------------------------------------------
extern "C" void kernel_launch(void* const* d_in, const int* in_sizes, int n_in,
                              void* d_out, int out_size, void* d_ws, size_t ws_size,
                              hipStream_t stream)
{
    const float* x      = (const float*)d_in[0];
    const int*   ei     = (const int*)d_in[1];
    const float* eat0   = (const float*)d_in[2];
    const float* msg_W0 = (const float*)d_in[3];
    const float* msg_b0 = (const float*)d_in[4];
    const float* msg_W1 = (const float*)d_in[5];
    const float* msg_b1 = (const float*)d_in[6];
    const float* msg_W2 = (const float*)d_in[7];
    const float* msg_b2 = (const float*)d_in[8];
    const float* n0g    = (const float*)d_in[9];
    const float* n0b    = (const float*)d_in[10];
    const float* ff_W0  = (const float*)d_in[11];
    const float* ff_b0  = (const float*)d_in[12];
    const float* ff_W1  = (const float*)d_in[13];
    const float* ff_b1  = (const float*)d_in[14];
    const float* n1g    = (const float*)d_in[15];
    const float* n1b    = (const float*)d_in[16];
    const float* e_W0   = (const float*)d_in[17];
    const float* e_b0   = (const float*)d_in[18];
    const float* e_W1   = (const float*)d_in[19];
    const float* e_b1   = (const float*)d_in[20];
    const float* e_W2   = (const float*)d_in[21];
    const float* e_b2   = (const float*)d_in[22];
    const float* eng    = (const float*)d_in[23];
    const float* enb    = (const float*)d_in[24];

    char* ws = (char*)d_ws;
    const size_t MB = (size_t)1 << 20;
    unsigned short* nodes = (unsigned short*)(ws);                 // 8 MB bf16
    unsigned short* edgec = (unsigned short*)(ws + 8 * MB);        // 64 MB bf16
    unsigned short* tmpA  = (unsigned short*)(ws + 72 * MB);       // 64 MB (msg out m)
    unsigned short* ffh   = (unsigned short*)(ws + 136 * MB);      // 32 MB (FF hidden)
    unsigned short* ffo   = tmpA;                                  // alias (phase-disjoint)
    unsigned short* wt    = (unsigned short*)(ws + 200 * MB);      // ~1 MB bf16
    int*            deg   = (int*)(ws + 202 * MB);                 // 128 KB
    int*            off   = (int*)(ws + 202 * MB + 256 * 1024);    // 128 KB + 4
    int*            cur   = (int*)(ws + 202 * MB + 512 * 1024);    // 128 KB
    int*            elist = (int*)(ws + 202 * MB + 768 * 1024);    // 1 MB

    // weight transpose targets (bf16 [N][K])
    unsigned short* p = wt;
    unsigned short *wt_m0[L_], *wt_m1[L_], *wt_m2[L_], *wt_f0[L_], *wt_f1[L_];
    for (int l = 0; l < L_; ++l) {
        wt_m0[l] = p; p += 384 * 128;
        wt_m1[l] = p; p += 128 * 128;
        wt_m2[l] = p; p += 128 * 128;
        wt_f0[l] = p; p += 128 * 512;
        wt_f1[l] = p; p += 512 * 128;
    }
    unsigned short* wt_e0 = p; p += 384 * 128;
    unsigned short* wt_e1 = p; p += 128 * 128;
    unsigned short* wt_e2 = p; p += 128 * 128;

    TDA tda; int toff = 0, ti = 0;
    auto addT = [&](const float* s, unsigned short* d, int K, int N) {
        tda.v[ti++] = TD{s, d, toff, K, (N == 512 ? 9 : 7)};
        toff += K * N;
    };
    for (int l = 0; l < L_; ++l) {
        addT(msg_W0 + l * 384 * 128, wt_m0[l], 384, 128);
        addT(msg_W1 + l * 128 * 128, wt_m1[l], 128, 128);
        addT(msg_W2 + l * 128 * 128, wt_m2[l], 128, 128);
        addT(ff_W0  + l * 128 * 512, wt_f0[l], 128, 512);
        addT(ff_W1  + l * 512 * 128, wt_f1[l], 512, 128);
    }
    addT(e_W0, wt_e0, 384, 128);   // layer-0 edge update only (layer-1's is dead code)
    addT(e_W1, wt_e1, 128, 128);
    addT(e_W2, wt_e2, 128, 128);
    tda.total = toff;
    k_transpose_all<<<(toff + 255) / 256, 256, 0, stream>>>(tda);

    const int n4a = NNODES * 128 / 4, n4b = E_ * 128 / 4;
    k_cvt2<<<(n4a + n4b + 255) / 256, 256, 0, stream>>>(x, nodes, n4a, eat0, edgec, n4b);

    // CSR build (once — edge_index constant across layers)
    hipMemsetAsync(deg, 0, NNODES * sizeof(int), stream);
    k_deg<<<E_ / 256, 256, 0, stream>>>(ei, deg);
    k_scan<<<1, 1024, 0, stream>>>(deg, off);
    hipMemcpyAsync(cur, off, NNODES * sizeof(int), hipMemcpyDeviceToDevice, stream);
    k_bucket<<<E_ / 256, 256, 0, stream>>>(ei, cur, elist);

    const dim3 gE(E_ / 64, 1), gN64(NNODES / 64, 1), gF0(NNODES / 128, 4);

    for (int l = 0; l < L_; ++l) {
        // --- fused message MLP (3 GEMMs in one kernel) -> m ---
        fused_mlp3<false><<<gE, 256, 0, stream>>>(nodes, edgec, ei,
            wt_m0[l], wt_m1[l], wt_m2[l],
            msg_b0 + l * 128, msg_b1 + l * 128, msg_b2 + l * 128,
            nullptr, nullptr, tmpA);
        k_aggln<<<NNODES / 4, 256, 0, stream>>>(tmpA, off, elist, nodes,
            n0g + l * 128, n0b + l * 128, nodes);
        // --- feedforward + LN ---
        mlp_gemm<128, 128, 512, true ><<<gF0, 256, 0, stream>>>(nodes, wt_f0[l], ff_b0 + l * 512, ffh);
        mlp_gemm<64,  512, 128, false><<<gN64, 256, 0, stream>>>(ffh, wt_f1[l], ff_b1 + l * 128, ffo);
        if (l == L_ - 1) {
            k_ln<true ><<<NNODES / 4, 256, 0, stream>>>(nodes, ffo, n1g + l * 128, n1b + l * 128, d_out);
        } else {
            k_ln<false><<<NNODES / 4, 256, 0, stream>>>(nodes, ffo, n1g + l * 128, n1b + l * 128, nodes);
        }
        // --- fused edge update incl. residual+LN (only layer 0; layer-1's is dead) ---
        if (l == 0) {
            fused_mlp3<true><<<gE, 256, 0, stream>>>(nodes, edgec, ei,
                wt_e0, wt_e1, wt_e2, e_b0, e_b1, e_b2, eng, enb, edgec);
        }
    }
}